// Round 8
// baseline (386.276 us; speedup 1.0000x reference)
//
#include <hip/hip_runtime.h>
#include <hip/hip_bf16.h>
#include <stdint.h>

#define B_TOT 262144

typedef __attribute__((ext_vector_type(8))) short bf8;
typedef __attribute__((ext_vector_type(16))) float f32x16;

__device__ __forceinline__ float bf2f(uint32_t u)   { return __uint_as_float(u << 16); }
__device__ __forceinline__ float bfhi2f(uint32_t u) { return __uint_as_float(u & 0xffff0000u); }
__device__ __forceinline__ uint32_t f2bf(float x) {
  uint32_t u = __float_as_uint(x);
  return (u + 0x7fffu + ((u >> 16) & 1u)) >> 16;   // RTN-even
}
__device__ __forceinline__ uint32_t pkbf(float lo, float hi) {
  union { __hip_bfloat162 b; uint32_t u; } c;
  c.b = __float22bfloat162_rn(make_float2(lo, hi));
  return c.u;
}
__device__ __forceinline__ bf8 mkfrag(uint32_t w0, uint32_t w1, uint32_t w2, uint32_t w3) {
  union { uint32_t u[4]; bf8 v; } c;
  c.u[0] = w0; c.u[1] = w1; c.u[2] = w2; c.u[3] = w3;
  return c.v;
}

// ---------------- prep: adj counts, W frags (true k-map), W@a score vectors ----------
// A/B frag k-mapping for mfma_32x32x16: lane l, elem e: k = 8*(e>>2)+4*(l>>5)+(e&3).
__global__ __launch_bounds__(256) void prep_kernel(
    const int* __restrict__ adj,
    const float* __restrict__ W1, const float* __restrict__ a1s, const float* __restrict__ a1d,
    const float* __restrict__ W2, const float* __restrict__ a2s, const float* __restrict__ a2d,
    const float* __restrict__ Wo1, const float* __restrict__ Wo2,
    uint32_t* __restrict__ cntp, uint16_t* __restrict__ W1F, uint16_t* __restrict__ W2F,
    uint16_t* __restrict__ Wo1F, uint16_t* __restrict__ Wo2F, float* __restrict__ wvec)
{
  const int gid = blockIdx.x * 256 + threadIdx.x;
  if (gid < B_TOT) {
    uint32_t cpv = 0;
    const int* ap = adj + (size_t)gid * 9;
    #pragma unroll
    for (int i = 0; i < 3; ++i)
      #pragma unroll
      for (int j = 0; j < 3; ++j) {
        uint32_t c = (uint32_t)ap[j * 3 + i] + (i == j ? 1u : 0u);  // adj^T + I
        cpv |= c << (2 * (3 * i + j));
      }
    cntp[gid] = cpv;
  }
  const int e = gid & 7, li = (gid >> 3) & 63;
  const int kfrag = 8 * (e >> 2) + 4 * (li >> 5) + (e & 3);
  if (gid < 3072) {   // W1^T frags [ks3][t2]
    const int f = gid >> 9, t = f & 1, ks = f >> 1;
    const int k = ks * 16 + kfrag, row = t * 32 + (li & 31);
    W1F[gid] = (uint16_t)f2bf(k < 35 ? W1[k * 64 + row] : 0.f);
  }
  if (gid < 4096) {   // W2^T frags [ks4][t2]
    const int f = gid >> 9, t = f & 1, ks = f >> 1;
    const int k = ks * 16 + kfrag, row = t * 32 + (li & 31);
    W2F[gid] = (uint16_t)f2bf(W2[k * 64 + row]);
  }
  if (gid < 49152) {  // Wo1^T frags [ks12][t8]
    const int rr = gid >> 9, t = rr & 7, ks = rr >> 3;
    const int k = ks * 16 + kfrag, col = t * 32 + (li & 31);
    Wo1F[gid] = (uint16_t)f2bf(Wo1[k * 256 + col]);
  }
  if (gid < 32768) {  // Wo2^T frags [ks16][t4]
    const int rr = gid >> 9, t = rr & 3, ks = rr >> 2;
    const int k = ks * 16 + kfrag, col = t * 32 + (li & 31);
    Wo2F[gid] = (uint16_t)f2bf(Wo2[k * 128 + col]);
  }
  if (gid < 224) {    // score vectors: [0..63]=W1@a1s (pad), [64..127]=W1@a1d, [128..191]=W2@a2s, [192..255]=W2@a2d
    if (gid < 48) {
      float s = 0.f; if (gid < 35) for (int d = 0; d < 64; ++d) s += W1[gid * 64 + d] * a1s[d];
      wvec[gid] = s;
    } else if (gid < 96) {
      const int k = gid - 48; float s = 0.f;
      if (k < 35) for (int d = 0; d < 64; ++d) s += W1[k * 64 + d] * a1d[d];
      wvec[64 + k] = s;
    } else if (gid < 160) {
      const int k = gid - 96; float s = 0.f;
      for (int d = 0; d < 64; ++d) s += W2[k * 64 + d] * a2s[d];
      wvec[128 + k] = s;
    } else {
      const int k = gid - 160; float s = 0.f;
      for (int d = 0; d < 64; ++d) s += W2[k * 64 + d] * a2d[d];
      wvec[192 + k] = s;
    }
  }
}

// ---------------- attention: softmax + aggregate; result -> per-thread LDS column ----
// phc[w<<8] = word w = i*16 + t*8 + p  (pairwise-packed C regs in reg order); because
// C-row formula == B-frag k formula, words [4ks..4ks+3] ARE the B-frag of k-tile ks.
template<bool DO_ELU, bool NS>
__device__ __forceinline__ void attention(const f32x16 (&az)[3][2],
    const float (&ss)[3], const float (&sd)[3], uint32_t cp, int hi,
    const float* __restrict__ bvec, const float* __restrict__ nxs, const float* __restrict__ nxd,
    uint32_t* phc, float (&ss2)[3], float (&sd2)[3])
{
  float al[3][3];
  #pragma unroll
  for (int i = 0; i < 3; ++i) {
    float ev[3]; float mx = -1e30f;
    #pragma unroll
    for (int j = 0; j < 3; ++j) {
      float s = ss[j] + sd[i];
      s = fmaxf(s, 0.2f * s);              // leaky_relu 0.2
      ev[j] = s;
      int c = (cp >> (2 * (3 * i + j))) & 3;
      mx = fmaxf(mx, c ? s : -1e30f);
    }
    float sum = 0.f;
    #pragma unroll
    for (int j = 0; j < 3; ++j) {
      int c = (cp >> (2 * (3 * i + j))) & 3;
      float p = (float)c * __expf(ev[j] - mx);
      al[i][j] = p; sum += p;
    }
    float inv = 1.0f / sum;
    #pragma unroll
    for (int j = 0; j < 3; ++j) al[i][j] *= inv;
  }
  #pragma unroll
  for (int t = 0; t < 2; ++t) {
    float bv[16], nsv[16], ndv[16];
    #pragma unroll
    for (int rq = 0; rq < 4; ++rq) {
      float4 b4 = *reinterpret_cast<const float4*>(bvec + t * 32 + rq * 8 + hi * 4);
      bv[4 * rq + 0] = b4.x; bv[4 * rq + 1] = b4.y; bv[4 * rq + 2] = b4.z; bv[4 * rq + 3] = b4.w;
      if (NS) {
        float4 s4 = *reinterpret_cast<const float4*>(nxs + t * 32 + rq * 8 + hi * 4);
        float4 d4 = *reinterpret_cast<const float4*>(nxd + t * 32 + rq * 8 + hi * 4);
        nsv[4 * rq + 0] = s4.x; nsv[4 * rq + 1] = s4.y; nsv[4 * rq + 2] = s4.z; nsv[4 * rq + 3] = s4.w;
        ndv[4 * rq + 0] = d4.x; ndv[4 * rq + 1] = d4.y; ndv[4 * rq + 2] = d4.z; ndv[4 * rq + 3] = d4.w;
      }
    }
    #pragma unroll
    for (int i = 0; i < 3; ++i) {
      float hv[16];
      #pragma unroll
      for (int r = 0; r < 16; ++r) {
        float v = bv[r];
        v = fmaf(al[i][0], az[0][t][r], v);
        v = fmaf(al[i][1], az[1][t][r], v);
        v = fmaf(al[i][2], az[2][t][r], v);
        if (DO_ELU) v = v > 0.f ? v : (__expf(v) - 1.f);
        if (NS) { ss2[i] = fmaf(v, nsv[r], ss2[i]); sd2[i] = fmaf(v, ndv[r], sd2[i]); }
        hv[r] = v;
      }
      #pragma unroll
      for (int p = 0; p < 8; ++p)
        phc[(i * 16 + t * 8 + p) << 8] = pkbf(hv[2 * p], hv[2 * p + 1]);
    }
  }
}

// -------- fused GAT+MLP: 32 elem/wave; FULL unroll; LDS = 48KB ph columns, 0 barriers --
__global__ __launch_bounds__(256, 3) void fused_kernel(
    const float* __restrict__ obs, const float* __restrict__ act,
    const uint32_t* __restrict__ cntp,
    const uint16_t* __restrict__ W1F, const uint16_t* __restrict__ W2F,
    const float* __restrict__ b1, const float* __restrict__ b2,
    const uint16_t* __restrict__ Wo1F, const float* __restrict__ bo1,
    const float* __restrict__ g1, const float* __restrict__ be1,
    const uint16_t* __restrict__ Wo2F, const float* __restrict__ bo2,
    const float* __restrict__ g2, const float* __restrict__ be2,
    const float* __restrict__ Wo3, const float* __restrict__ bo3,
    const float* __restrict__ wvec, float* __restrict__ out)
{
  __shared__ uint32_t ph[48 * 256];   // thread-private columns; never any __syncthreads
  const int tid = threadIdx.x;
  uint32_t* phc = ph + tid;

  const int l = tid & 63, hi = l >> 5, col = l & 31;
  const int wid = blockIdx.x * 4 + (tid >> 6);
  const int e = wid * 32 + col;
  const uint32_t cp = cntp[e];
  const float* obs_e = obs + (size_t)e * 90;
  const float* act_e = act + (size_t)e * 15;

  // ===== GAT layer 1 (x split hi+lo bf16; per-lane f32 score dots) =====
  f32x16 az[3][2];
  #pragma unroll
  for (int n = 0; n < 3; ++n)
    #pragma unroll
    for (int t = 0; t < 2; ++t)
      #pragma unroll
      for (int r = 0; r < 16; ++r) az[n][t][r] = 0.f;
  float ss1[3] = {0, 0, 0}, sd1[3] = {0, 0, 0};

  #pragma unroll
  for (int ks = 0; ks < 3; ++ks) {
    bf8 xh[3], xl[3];
    #pragma unroll
    for (int n = 0; n < 3; ++n) {
      const float* on = obs_e + n * 30;
      float xv[8];
      #pragma unroll
      for (int r2 = 0; r2 < 2; ++r2) {
        if (ks == 2 && r2 == 1) { xv[4] = xv[5] = xv[6] = xv[7] = 0.f; continue; }
        const int kb = ks * 16 + r2 * 8 + hi * 4;
        #pragma unroll
        for (int j = 0; j < 4; ++j) {
          const int k = kb + j;
          float v = 0.f;
          if (k < 30) v = on[k];
          else if (k < 35) v = act_e[n * 5 + (k - 30)];
          xv[r2 * 4 + j] = v;
        }
        float4 s4 = *reinterpret_cast<const float4*>(wvec + kb);
        float4 d4 = *reinterpret_cast<const float4*>(wvec + 64 + kb);
        ss1[n] = fmaf(xv[r2 * 4 + 0], s4.x, ss1[n]); sd1[n] = fmaf(xv[r2 * 4 + 0], d4.x, sd1[n]);
        ss1[n] = fmaf(xv[r2 * 4 + 1], s4.y, ss1[n]); sd1[n] = fmaf(xv[r2 * 4 + 1], d4.y, sd1[n]);
        ss1[n] = fmaf(xv[r2 * 4 + 2], s4.z, ss1[n]); sd1[n] = fmaf(xv[r2 * 4 + 2], d4.z, sd1[n]);
        ss1[n] = fmaf(xv[r2 * 4 + 3], s4.w, ss1[n]); sd1[n] = fmaf(xv[r2 * 4 + 3], d4.w, sd1[n]);
      }
      uint32_t hw[4], lw[4];
      #pragma unroll
      for (int p = 0; p < 4; ++p) {
        hw[p] = pkbf(xv[2 * p], xv[2 * p + 1]);
        float ra = xv[2 * p]     - bf2f(hw[p]);
        float rb = xv[2 * p + 1] - bfhi2f(hw[p]);
        lw[p] = (__float_as_uint(ra) >> 16) | (__float_as_uint(rb) & 0xffff0000u);
      }
      xh[n] = mkfrag(hw[0], hw[1], hw[2], hw[3]);
      xl[n] = mkfrag(lw[0], lw[1], lw[2], lw[3]);
    }
    #pragma unroll
    for (int t = 0; t < 2; ++t) {
      bf8 a = *reinterpret_cast<const bf8*>(W1F + (size_t)(ks * 2 + t) * 512 + l * 8);
      #pragma unroll
      for (int n = 0; n < 3; ++n) {
        az[n][t] = __builtin_amdgcn_mfma_f32_32x32x16_bf16(a, xh[n], az[n][t], 0, 0, 0);
        az[n][t] = __builtin_amdgcn_mfma_f32_32x32x16_bf16(a, xl[n], az[n][t], 0, 0, 0);
      }
    }
  }
  #pragma unroll
  for (int n = 0; n < 3; ++n) {
    ss1[n] += __shfl_xor(ss1[n], 32);
    sd1[n] += __shfl_xor(sd1[n], 32);
  }

  float ss2[3] = {0, 0, 0}, sd2[3] = {0, 0, 0};
  attention<true, true>(az, ss1, sd1, cp, hi, b1, wvec + 128, wvec + 192, phc, ss2, sd2);
  #pragma unroll
  for (int n = 0; n < 3; ++n) {
    ss2[n] += __shfl_xor(ss2[n], 32);
    sd2[n] += __shfl_xor(sd2[n], 32);
  }

  // ===== GAT layer 2 (B-frags from ph columns) =====
  f32x16 a2[3][2];
  #pragma unroll
  for (int n = 0; n < 3; ++n)
    #pragma unroll
    for (int t = 0; t < 2; ++t)
      #pragma unroll
      for (int r = 0; r < 16; ++r) a2[n][t][r] = 0.f;
  #pragma unroll
  for (int ks = 0; ks < 4; ++ks) {
    bf8 br[3];
    #pragma unroll
    for (int n = 0; n < 3; ++n) {
      const int wb = (n * 16 + ks * 4) << 8;
      br[n] = mkfrag(phc[wb], phc[wb + 256], phc[wb + 512], phc[wb + 768]);
    }
    #pragma unroll
    for (int t = 0; t < 2; ++t) {
      bf8 a = *reinterpret_cast<const bf8*>(W2F + (size_t)(ks * 2 + t) * 512 + l * 8);
      #pragma unroll
      for (int n = 0; n < 3; ++n)
        a2[n][t] = __builtin_amdgcn_mfma_f32_32x32x16_bf16(a, br[n], a2[n][t], 0, 0, 0);
    }
  }

  float du1[3], du2[3];
  attention<false, false>(a2, ss2, sd2, cp, hi, b2, nullptr, nullptr, phc, du1, du2);

  // ===== MLP layer 1: four quarters of 64 features; B-frags from ph columns =====
  float sm = 0.f, sq = 0.f;
  uint32_t y[64];
  #pragma unroll
  for (int q = 0; q < 4; ++q) {
    f32x16 acc[2];
    #pragma unroll
    for (int t = 0; t < 2; ++t)
      #pragma unroll
      for (int rq = 0; rq < 4; ++rq) {
        float4 b4 = *reinterpret_cast<const float4*>(bo1 + (q * 2 + t) * 32 + rq * 8 + hi * 4);
        acc[t][4 * rq + 0] = b4.x; acc[t][4 * rq + 1] = b4.y;
        acc[t][4 * rq + 2] = b4.z; acc[t][4 * rq + 3] = b4.w;
      }
    #pragma unroll
    for (int ks = 0; ks < 12; ++ks) {
      const int wb = ((ks >> 2) * 16 + (ks & 3) * 4) << 8;
      bf8 br_ = mkfrag(phc[wb], phc[wb + 256], phc[wb + 512], phc[wb + 768]);
      const uint16_t* wp = Wo1F + (size_t)(ks * 8 + q * 2) * 512 + l * 8;
      #pragma unroll
      for (int t = 0; t < 2; ++t) {
        bf8 a = *reinterpret_cast<const bf8*>(wp + t * 512);
        acc[t] = __builtin_amdgcn_mfma_f32_32x32x16_bf16(a, br_, acc[t], 0, 0, 0);
      }
    }
    #pragma unroll
    for (int t = 0; t < 2; ++t) {
      #pragma unroll
      for (int r = 0; r < 16; ++r) { const float v = acc[t][r]; sm += v; sq = fmaf(v, v, sq); }
      #pragma unroll
      for (int p = 0; p < 8; ++p)
        y[(q * 2 + t) * 8 + p] = pkbf(acc[t][2 * p], acc[t][2 * p + 1]);
    }
  }
  sm += __shfl_xor(sm, 32); sq += __shfl_xor(sq, 32);
  float mu = sm * (1.f / 256.f);
  float rr = rsqrtf(sq * (1.f / 256.f) - mu * mu + 1e-5f);
  #pragma unroll
  for (int tg = 0; tg < 8; ++tg)
    #pragma unroll
    for (int rq = 0; rq < 4; ++rq) {
      float4 gg = *reinterpret_cast<const float4*>(g1 + tg * 32 + rq * 8 + hi * 4);
      float4 bb = *reinterpret_cast<const float4*>(be1 + tg * 32 + rq * 8 + hi * 4);
      const int w0 = tg * 8 + rq * 2;
      float v0 = (bf2f(y[w0]) - mu) * rr * gg.x + bb.x;        v0 = fmaxf(v0, 0.01f * v0);
      float v1 = (bfhi2f(y[w0]) - mu) * rr * gg.y + bb.y;      v1 = fmaxf(v1, 0.01f * v1);
      y[w0] = pkbf(v0, v1);
      float v2 = (bf2f(y[w0 + 1]) - mu) * rr * gg.z + bb.z;    v2 = fmaxf(v2, 0.01f * v2);
      float v3 = (bfhi2f(y[w0 + 1]) - mu) * rr * gg.w + bb.w;  v3 = fmaxf(v3, 0.01f * v3);
      y[w0 + 1] = pkbf(v2, v3);
    }

  // ===== MLP layer 2 (Wo2F from global/L2; y static in regs) =====
  f32x16 acc2[4];
  #pragma unroll
  for (int t = 0; t < 4; ++t)
    #pragma unroll
    for (int rq = 0; rq < 4; ++rq) {
      float4 b4 = *reinterpret_cast<const float4*>(bo2 + t * 32 + rq * 8 + hi * 4);
      acc2[t][4 * rq + 0] = b4.x; acc2[t][4 * rq + 1] = b4.y;
      acc2[t][4 * rq + 2] = b4.z; acc2[t][4 * rq + 3] = b4.w;
    }
  #pragma unroll
  for (int ks = 0; ks < 16; ++ks) {
    bf8 br_ = mkfrag(y[4 * ks], y[4 * ks + 1], y[4 * ks + 2], y[4 * ks + 3]);
    #pragma unroll
    for (int t = 0; t < 4; ++t) {
      bf8 a = *reinterpret_cast<const bf8*>(Wo2F + (size_t)(ks * 4 + t) * 512 + l * 8);
      acc2[t] = __builtin_amdgcn_mfma_f32_32x32x16_bf16(a, br_, acc2[t], 0, 0, 0);
    }
  }
  // LN(128) + lrelu + final dot with Wo3
  sm = 0.f; sq = 0.f;
  #pragma unroll
  for (int t = 0; t < 4; ++t)
    #pragma unroll
    for (int r = 0; r < 16; ++r) { const float v = acc2[t][r]; sm += v; sq = fmaf(v, v, sq); }
  sm += __shfl_xor(sm, 32); sq += __shfl_xor(sq, 32);
  mu = sm * (1.f / 128.f);
  rr = rsqrtf(sq * (1.f / 128.f) - mu * mu + 1e-5f);
  float acy = 0.f;
  #pragma unroll
  for (int t = 0; t < 4; ++t)
    #pragma unroll
    for (int rq = 0; rq < 4; ++rq) {
      float4 gg = *reinterpret_cast<const float4*>(g2 + t * 32 + rq * 8 + hi * 4);
      float4 bb = *reinterpret_cast<const float4*>(be2 + t * 32 + rq * 8 + hi * 4);
      float4 ww = *reinterpret_cast<const float4*>(Wo3 + t * 32 + rq * 8 + hi * 4);
      float v;
      v = (acc2[t][4 * rq + 0] - mu) * rr * gg.x + bb.x; acy = fmaf(fmaxf(v, 0.01f * v), ww.x, acy);
      v = (acc2[t][4 * rq + 1] - mu) * rr * gg.y + bb.y; acy = fmaf(fmaxf(v, 0.01f * v), ww.y, acy);
      v = (acc2[t][4 * rq + 2] - mu) * rr * gg.z + bb.z; acy = fmaf(fmaxf(v, 0.01f * v), ww.z, acy);
      v = (acc2[t][4 * rq + 3] - mu) * rr * gg.w + bb.w; acy = fmaf(fmaxf(v, 0.01f * v), ww.w, acy);
    }
  acy += __shfl_xor(acy, 32);
  if (hi == 0) out[e] = acy + bo3[0];
}

extern "C" void kernel_launch(void* const* d_in, const int* in_sizes, int n_in,
                              void* d_out, int out_size, void* d_ws, size_t ws_size,
                              hipStream_t stream) {
  const float* obs  = (const float*)d_in[0];
  const float* actn = (const float*)d_in[1];
  const int*   adj  = (const int*)d_in[2];
  const float* W1   = (const float*)d_in[3];
  const float* a1s  = (const float*)d_in[4];
  const float* a1d  = (const float*)d_in[5];
  const float* b1   = (const float*)d_in[6];
  const float* W2   = (const float*)d_in[7];
  const float* a2s  = (const float*)d_in[8];
  const float* a2d  = (const float*)d_in[9];
  const float* b2   = (const float*)d_in[10];
  const float* Wo1  = (const float*)d_in[11];
  const float* bo1  = (const float*)d_in[12];
  const float* g1   = (const float*)d_in[13];
  const float* be1  = (const float*)d_in[14];
  const float* Wo2  = (const float*)d_in[15];
  const float* bo2  = (const float*)d_in[16];
  const float* g2   = (const float*)d_in[17];
  const float* be2  = (const float*)d_in[18];
  const float* Wo3  = (const float*)d_in[19];
  const float* bo3  = (const float*)d_in[20];

  char* ws = (char*)d_ws;
  uint32_t* cntp = (uint32_t*)ws;                       // 1 MB
  uint16_t* W1F  = (uint16_t*)(ws + 1048576);           // 6144 B
  uint16_t* W2F  = (uint16_t*)(ws + 1048576 + 8192);    // 8192 B
  uint16_t* Wo1F = (uint16_t*)(ws + 1048576 + 16384);   // 98304 B
  uint16_t* Wo2F = (uint16_t*)(ws + 1048576 + 114688);  // 65536 B
  float*    wvec = (float*)(ws + 1048576 + 180224);     // 1024 B
  float* outp = (float*)d_out;

  prep_kernel<<<1024, 256, 0, stream>>>(adj, W1, a1s, a1d, W2, a2s, a2d, Wo1, Wo2,
                                        cntp, W1F, W2F, Wo1F, Wo2F, wvec);
  fused_kernel<<<2048, 256, 0, stream>>>(obs, actn, cntp, W1F, W2F, b1, b2,
                                         Wo1F, bo1, g1, be1, Wo2F, bo2, g2, be2,
                                         Wo3, bo3, wvec, outp);
}

// Round 9
// 210.213 us; speedup vs baseline: 1.8375x; 1.8375x over previous
//
#include <hip/hip_runtime.h>
#include <hip/hip_bf16.h>
#include <stdint.h>

#define B_TOT 262144

typedef __attribute__((ext_vector_type(8))) short bf8;
typedef __attribute__((ext_vector_type(16))) float f32x16;

__device__ __forceinline__ float bf2f(uint32_t u)   { return __uint_as_float(u << 16); }
__device__ __forceinline__ float bfhi2f(uint32_t u) { return __uint_as_float(u & 0xffff0000u); }
__device__ __forceinline__ uint32_t f2bf(float x) {
  uint32_t u = __float_as_uint(x);
  return (u + 0x7fffu + ((u >> 16) & 1u)) >> 16;   // RTN-even
}
__device__ __forceinline__ uint32_t pkbf(float lo, float hi) {
  union { __hip_bfloat162 b; uint32_t u; } c;
  c.b = __float22bfloat162_rn(make_float2(lo, hi));
  return c.u;
}
__device__ __forceinline__ bf8 mkfrag(uint32_t w0, uint32_t w1, uint32_t w2, uint32_t w3) {
  union { uint32_t u[4]; bf8 v; } c;
  c.u[0] = w0; c.u[1] = w1; c.u[2] = w2; c.u[3] = w3;
  return c.v;
}

// ---------------- prep: adj counts, W frags (true k-map), W@a score vectors ----------
// A/B frag k-mapping for mfma_32x32x16: lane l, elem e: k = 8*(e>>2)+4*(l>>5)+(e&3).
__global__ __launch_bounds__(256) void prep_kernel(
    const int* __restrict__ adj,
    const float* __restrict__ W1, const float* __restrict__ a1s, const float* __restrict__ a1d,
    const float* __restrict__ W2, const float* __restrict__ a2s, const float* __restrict__ a2d,
    const float* __restrict__ Wo1, const float* __restrict__ Wo2,
    uint32_t* __restrict__ cntp, uint16_t* __restrict__ W1F, uint16_t* __restrict__ W2F,
    uint16_t* __restrict__ Wo1F, uint16_t* __restrict__ Wo2F, float* __restrict__ wvec)
{
  const int gid = blockIdx.x * 256 + threadIdx.x;
  if (gid < B_TOT) {
    uint32_t cpv = 0;
    const int* ap = adj + (size_t)gid * 9;
    #pragma unroll
    for (int i = 0; i < 3; ++i)
      #pragma unroll
      for (int j = 0; j < 3; ++j) {
        uint32_t c = (uint32_t)ap[j * 3 + i] + (i == j ? 1u : 0u);  // adj^T + I
        cpv |= c << (2 * (3 * i + j));
      }
    cntp[gid] = cpv;
  }
  const int e = gid & 7, li = (gid >> 3) & 63;
  const int kfrag = 8 * (e >> 2) + 4 * (li >> 5) + (e & 3);
  if (gid < 3072) {   // W1^T frags [ks3][t2]
    const int f = gid >> 9, t = f & 1, ks = f >> 1;
    const int k = ks * 16 + kfrag, row = t * 32 + (li & 31);
    W1F[gid] = (uint16_t)f2bf(k < 35 ? W1[k * 64 + row] : 0.f);
  }
  if (gid < 4096) {   // W2^T frags [ks4][t2]
    const int f = gid >> 9, t = f & 1, ks = f >> 1;
    const int k = ks * 16 + kfrag, row = t * 32 + (li & 31);
    W2F[gid] = (uint16_t)f2bf(W2[k * 64 + row]);
  }
  if (gid < 49152) {  // Wo1^T frags [ks12][t8]
    const int rr = gid >> 9, t = rr & 7, ks = rr >> 3;
    const int k = ks * 16 + kfrag, col = t * 32 + (li & 31);
    Wo1F[gid] = (uint16_t)f2bf(Wo1[k * 256 + col]);
  }
  if (gid < 32768) {  // Wo2^T frags [ks16][t4]
    const int rr = gid >> 9, t = rr & 3, ks = rr >> 2;
    const int k = ks * 16 + kfrag, col = t * 32 + (li & 31);
    Wo2F[gid] = (uint16_t)f2bf(Wo2[k * 128 + col]);
  }
  if (gid < 224) {    // score vectors: [0..63]=W1@a1s (pad), [64..127]=W1@a1d, [128..191]=W2@a2s, [192..255]=W2@a2d
    if (gid < 48) {
      float s = 0.f; if (gid < 35) for (int d = 0; d < 64; ++d) s += W1[gid * 64 + d] * a1s[d];
      wvec[gid] = s;
    } else if (gid < 96) {
      const int k = gid - 48; float s = 0.f;
      if (k < 35) for (int d = 0; d < 64; ++d) s += W1[k * 64 + d] * a1d[d];
      wvec[64 + k] = s;
    } else if (gid < 160) {
      const int k = gid - 96; float s = 0.f;
      for (int d = 0; d < 64; ++d) s += W2[k * 64 + d] * a2s[d];
      wvec[128 + k] = s;
    } else {
      const int k = gid - 160; float s = 0.f;
      for (int d = 0; d < 64; ++d) s += W2[k * 64 + d] * a2d[d];
      wvec[192 + k] = s;
    }
  }
}

// ---------------- attention: given reduced ss/sd, softmax + aggregate (+ next scores) --
template<bool DO_ELU, bool NS>
__device__ __forceinline__ void attention(const f32x16 (&az)[3][2],
    const float (&ss)[3], const float (&sd)[3], uint32_t cp, int hi,
    const float* __restrict__ bvec, const float* __restrict__ nxs, const float* __restrict__ nxd,
    uint32_t (&Ph)[3][16], float (&ss2)[3], float (&sd2)[3])
{
  float al[3][3];
  #pragma unroll
  for (int i = 0; i < 3; ++i) {
    float ev[3]; float mx = -1e30f;
    #pragma unroll
    for (int j = 0; j < 3; ++j) {
      float s = ss[j] + sd[i];
      s = fmaxf(s, 0.2f * s);              // leaky_relu 0.2
      ev[j] = s;
      int c = (cp >> (2 * (3 * i + j))) & 3;
      mx = fmaxf(mx, c ? s : -1e30f);
    }
    float sum = 0.f;
    #pragma unroll
    for (int j = 0; j < 3; ++j) {
      int c = (cp >> (2 * (3 * i + j))) & 3;
      float p = (float)c * __expf(ev[j] - mx);
      al[i][j] = p; sum += p;
    }
    float inv = 1.0f / sum;
    #pragma unroll
    for (int j = 0; j < 3; ++j) al[i][j] *= inv;
  }
  #pragma unroll
  for (int t = 0; t < 2; ++t) {
    float bv[16], nsv[16], ndv[16];
    #pragma unroll
    for (int rq = 0; rq < 4; ++rq) {
      float4 b4 = *reinterpret_cast<const float4*>(bvec + t * 32 + rq * 8 + hi * 4);
      bv[4 * rq + 0] = b4.x; bv[4 * rq + 1] = b4.y; bv[4 * rq + 2] = b4.z; bv[4 * rq + 3] = b4.w;
      if (NS) {
        float4 s4 = *reinterpret_cast<const float4*>(nxs + t * 32 + rq * 8 + hi * 4);
        float4 d4 = *reinterpret_cast<const float4*>(nxd + t * 32 + rq * 8 + hi * 4);
        nsv[4 * rq + 0] = s4.x; nsv[4 * rq + 1] = s4.y; nsv[4 * rq + 2] = s4.z; nsv[4 * rq + 3] = s4.w;
        ndv[4 * rq + 0] = d4.x; ndv[4 * rq + 1] = d4.y; ndv[4 * rq + 2] = d4.z; ndv[4 * rq + 3] = d4.w;
      }
    }
    #pragma unroll
    for (int i = 0; i < 3; ++i) {
      float hv[16];
      #pragma unroll
      for (int r = 0; r < 16; ++r) {
        float v = bv[r];
        v = fmaf(al[i][0], az[0][t][r], v);
        v = fmaf(al[i][1], az[1][t][r], v);
        v = fmaf(al[i][2], az[2][t][r], v);
        if (DO_ELU) v = v > 0.f ? v : (__expf(v) - 1.f);
        if (NS) { ss2[i] = fmaf(v, nsv[r], ss2[i]); sd2[i] = fmaf(v, ndv[r], sd2[i]); }
        hv[r] = v;
      }
      #pragma unroll
      for (int p = 0; p < 8; ++p) Ph[i][t * 8 + p] = pkbf(hv[2 * p], hv[2 * p + 1]);
    }
  }
}

// ---- fused GAT+MLP: 32 elem/wave; x cooperatively staged in LDS (coalesced); Ph in regs
__global__ __launch_bounds__(256, 2) void fused_kernel(
    const float* __restrict__ obs, const float* __restrict__ act,
    const uint32_t* __restrict__ cntp,
    const uint16_t* __restrict__ W1F, const uint16_t* __restrict__ W2F,
    const float* __restrict__ b1, const float* __restrict__ b2,
    const uint16_t* __restrict__ Wo1F, const float* __restrict__ bo1,
    const float* __restrict__ g1, const float* __restrict__ be1,
    const uint16_t* __restrict__ Wo2F, const float* __restrict__ bo2,
    const float* __restrict__ g2, const float* __restrict__ be2,
    const float* __restrict__ Wo3, const float* __restrict__ bo3,
    const float* __restrict__ wvec, float* __restrict__ out)
{
  // per-wave x stage: [obs 2880 f][act 480 f][pad 32 f] = 3392 f = 13568 B; x4 waves = 54272 B
  __shared__ float xs[4 * 3392];
  const int tid = threadIdx.x;
  const int l = tid & 63, hi = l >> 5, col = l & 31;
  const int w = tid >> 6;
  const int wid = blockIdx.x * 4 + w;
  const int e = wid * 32 + col;
  float* xw = xs + w * 3392;

  // ---- cooperative coalesced staging: global (dwordx2) -> LDS (linear) ----
  {
    const uint2* __restrict__ og = (const uint2*)(obs + (size_t)(wid * 32) * 90);
    const uint2* __restrict__ ag = (const uint2*)(act + (size_t)(wid * 32) * 15);
    uint2* ow = (uint2*)xw;
    #pragma unroll
    for (int i = 0; i < 22; ++i) ow[l + 64 * i] = og[l + 64 * i];    // 1408 pairs
    if (l < 32) ow[1408 + l] = og[1408 + l];                         // tail -> 1440
    uint2* aw = (uint2*)(xw + 2880);
    #pragma unroll
    for (int i = 0; i < 3; ++i) aw[l + 64 * i] = ag[l + 64 * i];     // 192 pairs
    if (l < 48) aw[192 + l] = ag[192 + l];                           // tail -> 240
  }
  const uint32_t cp = cntp[e];

  // ===== GAT layer 1 (x split hi+lo bf16; per-lane f32 score dots); x from LDS =====
  f32x16 az[3][2];
  #pragma unroll
  for (int n = 0; n < 3; ++n)
    #pragma unroll
    for (int t = 0; t < 2; ++t)
      #pragma unroll
      for (int r = 0; r < 16; ++r) az[n][t][r] = 0.f;
  float ss1[3] = {0, 0, 0}, sd1[3] = {0, 0, 0};

  #pragma unroll
  for (int ks = 0; ks < 3; ++ks) {
    bf8 xh[3], xl[3];
    #pragma unroll
    for (int n = 0; n < 3; ++n) {
      float xv[8];
      #pragma unroll
      for (int r2 = 0; r2 < 2; ++r2) {
        if (ks == 2 && r2 == 1) { xv[4] = xv[5] = xv[6] = xv[7] = 0.f; continue; }
        const int kb = ks * 16 + r2 * 8 + hi * 4;
        #pragma unroll
        for (int j = 0; j < 4; ++j) {
          const int k = kb + j;
          const int off = (k < 30) ? (col * 90 + n * 30 + k)
                                   : (2880 + col * 15 + n * 5 + (k - 30));
          float v = xw[off];
          if (k >= 35) v = 0.f;
          xv[r2 * 4 + j] = v;
        }
        float4 s4 = *reinterpret_cast<const float4*>(wvec + kb);
        float4 d4 = *reinterpret_cast<const float4*>(wvec + 64 + kb);
        ss1[n] = fmaf(xv[r2 * 4 + 0], s4.x, ss1[n]); sd1[n] = fmaf(xv[r2 * 4 + 0], d4.x, sd1[n]);
        ss1[n] = fmaf(xv[r2 * 4 + 1], s4.y, ss1[n]); sd1[n] = fmaf(xv[r2 * 4 + 1], d4.y, sd1[n]);
        ss1[n] = fmaf(xv[r2 * 4 + 2], s4.z, ss1[n]); sd1[n] = fmaf(xv[r2 * 4 + 2], d4.z, sd1[n]);
        ss1[n] = fmaf(xv[r2 * 4 + 3], s4.w, ss1[n]); sd1[n] = fmaf(xv[r2 * 4 + 3], d4.w, sd1[n]);
      }
      uint32_t hw[4], lw[4];
      #pragma unroll
      for (int p = 0; p < 4; ++p) {
        hw[p] = pkbf(xv[2 * p], xv[2 * p + 1]);
        float ra = xv[2 * p]     - bf2f(hw[p]);
        float rb = xv[2 * p + 1] - bfhi2f(hw[p]);
        lw[p] = (__float_as_uint(ra) >> 16) | (__float_as_uint(rb) & 0xffff0000u);
      }
      xh[n] = mkfrag(hw[0], hw[1], hw[2], hw[3]);
      xl[n] = mkfrag(lw[0], lw[1], lw[2], lw[3]);
    }
    #pragma unroll
    for (int t = 0; t < 2; ++t) {
      bf8 a = *reinterpret_cast<const bf8*>(W1F + (size_t)(ks * 2 + t) * 512 + l * 8);
      #pragma unroll
      for (int n = 0; n < 3; ++n) {
        az[n][t] = __builtin_amdgcn_mfma_f32_32x32x16_bf16(a, xh[n], az[n][t], 0, 0, 0);
        az[n][t] = __builtin_amdgcn_mfma_f32_32x32x16_bf16(a, xl[n], az[n][t], 0, 0, 0);
      }
    }
  }
  #pragma unroll
  for (int n = 0; n < 3; ++n) {
    ss1[n] += __shfl_xor(ss1[n], 32);
    sd1[n] += __shfl_xor(sd1[n], 32);
  }

  uint32_t Ph1[3][16];
  float ss2[3] = {0, 0, 0}, sd2[3] = {0, 0, 0};
  attention<true, true>(az, ss1, sd1, cp, hi, b1, wvec + 128, wvec + 192, Ph1, ss2, sd2);
  #pragma unroll
  for (int n = 0; n < 3; ++n) {
    ss2[n] += __shfl_xor(ss2[n], 32);
    sd2[n] += __shfl_xor(sd2[n], 32);
  }

  // ===== GAT layer 2 =====
  f32x16 a2[3][2];
  #pragma unroll
  for (int n = 0; n < 3; ++n)
    #pragma unroll
    for (int t = 0; t < 2; ++t)
      #pragma unroll
      for (int r = 0; r < 16; ++r) a2[n][t][r] = 0.f;
  #pragma unroll
  for (int ks = 0; ks < 4; ++ks) {
    #pragma unroll
    for (int t = 0; t < 2; ++t) {
      bf8 a = *reinterpret_cast<const bf8*>(W2F + (size_t)(ks * 2 + t) * 512 + l * 8);
      #pragma unroll
      for (int n = 0; n < 3; ++n) {
        bf8 br_ = mkfrag(Ph1[n][4 * ks], Ph1[n][4 * ks + 1], Ph1[n][4 * ks + 2], Ph1[n][4 * ks + 3]);
        a2[n][t] = __builtin_amdgcn_mfma_f32_32x32x16_bf16(a, br_, a2[n][t], 0, 0, 0);
      }
    }
  }

  uint32_t Ph2[3][16];
  float du1[3], du2[3];
  attention<false, false>(a2, ss2, sd2, cp, hi, b2, nullptr, nullptr, Ph2, du1, du2);

  __syncthreads();   // align block's waves so the Wo1F stream reuses L1

  // ===== MLP layer 1: two halves of 128 features; pre-LN bf16 pack =====
  float sm = 0.f, sq = 0.f;
  uint32_t y[64];
  #pragma unroll
  for (int half = 0; half < 2; ++half) {
    f32x16 acc[4];
    #pragma unroll
    for (int t = 0; t < 4; ++t)
      #pragma unroll
      for (int rq = 0; rq < 4; ++rq) {
        float4 b4 = *reinterpret_cast<const float4*>(bo1 + (half * 4 + t) * 32 + rq * 8 + hi * 4);
        acc[t][4 * rq + 0] = b4.x; acc[t][4 * rq + 1] = b4.y;
        acc[t][4 * rq + 2] = b4.z; acc[t][4 * rq + 3] = b4.w;
      }
    #pragma unroll
    for (int ks = 0; ks < 12; ++ks) {
      const int n = ks >> 2, q0 = 4 * (ks & 3);
      bf8 br_ = mkfrag(Ph2[n][q0], Ph2[n][q0 + 1], Ph2[n][q0 + 2], Ph2[n][q0 + 3]);
      #pragma unroll
      for (int t = 0; t < 4; ++t) {
        bf8 a = *reinterpret_cast<const bf8*>(Wo1F + (size_t)(ks * 8 + half * 4 + t) * 512 + l * 8);
        acc[t] = __builtin_amdgcn_mfma_f32_32x32x16_bf16(a, br_, acc[t], 0, 0, 0);
      }
    }
    #pragma unroll
    for (int t = 0; t < 4; ++t) {
      #pragma unroll
      for (int r = 0; r < 16; ++r) { const float v = acc[t][r]; sm += v; sq = fmaf(v, v, sq); }
      #pragma unroll
      for (int p = 0; p < 8; ++p)
        y[(half * 4 + t) * 8 + p] = pkbf(acc[t][2 * p], acc[t][2 * p + 1]);
    }
  }
  sm += __shfl_xor(sm, 32); sq += __shfl_xor(sq, 32);
  float mu = sm * (1.f / 256.f);
  float rr = rsqrtf(sq * (1.f / 256.f) - mu * mu + 1e-5f);
  #pragma unroll
  for (int tg = 0; tg < 8; ++tg)
    #pragma unroll
    for (int rq = 0; rq < 4; ++rq) {
      float4 gg = *reinterpret_cast<const float4*>(g1 + tg * 32 + rq * 8 + hi * 4);
      float4 bb = *reinterpret_cast<const float4*>(be1 + tg * 32 + rq * 8 + hi * 4);
      const int w0 = tg * 8 + rq * 2;
      float v0 = (bf2f(y[w0]) - mu) * rr * gg.x + bb.x;        v0 = fmaxf(v0, 0.01f * v0);
      float v1 = (bfhi2f(y[w0]) - mu) * rr * gg.y + bb.y;      v1 = fmaxf(v1, 0.01f * v1);
      y[w0] = pkbf(v0, v1);
      float v2 = (bf2f(y[w0 + 1]) - mu) * rr * gg.z + bb.z;    v2 = fmaxf(v2, 0.01f * v2);
      float v3 = (bfhi2f(y[w0 + 1]) - mu) * rr * gg.w + bb.w;  v3 = fmaxf(v3, 0.01f * v3);
      y[w0 + 1] = pkbf(v2, v3);
    }

  // ===== MLP layer 2 (Wo2F from global/L2; y static in regs) =====
  f32x16 acc2[4];
  #pragma unroll
  for (int t = 0; t < 4; ++t)
    #pragma unroll
    for (int rq = 0; rq < 4; ++rq) {
      float4 b4 = *reinterpret_cast<const float4*>(bo2 + t * 32 + rq * 8 + hi * 4);
      acc2[t][4 * rq + 0] = b4.x; acc2[t][4 * rq + 1] = b4.y;
      acc2[t][4 * rq + 2] = b4.z; acc2[t][4 * rq + 3] = b4.w;
    }
  #pragma unroll
  for (int ks = 0; ks < 16; ++ks) {
    bf8 br_ = mkfrag(y[4 * ks], y[4 * ks + 1], y[4 * ks + 2], y[4 * ks + 3]);
    #pragma unroll
    for (int t = 0; t < 4; ++t) {
      bf8 a = *reinterpret_cast<const bf8*>(Wo2F + (size_t)(ks * 4 + t) * 512 + l * 8);
      acc2[t] = __builtin_amdgcn_mfma_f32_32x32x16_bf16(a, br_, acc2[t], 0, 0, 0);
    }
  }
  // LN(128) + lrelu + final dot with Wo3
  sm = 0.f; sq = 0.f;
  #pragma unroll
  for (int t = 0; t < 4; ++t)
    #pragma unroll
    for (int r = 0; r < 16; ++r) { const float v = acc2[t][r]; sm += v; sq = fmaf(v, v, sq); }
  sm += __shfl_xor(sm, 32); sq += __shfl_xor(sq, 32);
  mu = sm * (1.f / 128.f);
  rr = rsqrtf(sq * (1.f / 128.f) - mu * mu + 1e-5f);
  float acy = 0.f;
  #pragma unroll
  for (int t = 0; t < 4; ++t)
    #pragma unroll
    for (int rq = 0; rq < 4; ++rq) {
      float4 gg = *reinterpret_cast<const float4*>(g2 + t * 32 + rq * 8 + hi * 4);
      float4 bb = *reinterpret_cast<const float4*>(be2 + t * 32 + rq * 8 + hi * 4);
      float4 ww = *reinterpret_cast<const float4*>(Wo3 + t * 32 + rq * 8 + hi * 4);
      float v;
      v = (acc2[t][4 * rq + 0] - mu) * rr * gg.x + bb.x; acy = fmaf(fmaxf(v, 0.01f * v), ww.x, acy);
      v = (acc2[t][4 * rq + 1] - mu) * rr * gg.y + bb.y; acy = fmaf(fmaxf(v, 0.01f * v), ww.y, acy);
      v = (acc2[t][4 * rq + 2] - mu) * rr * gg.z + bb.z; acy = fmaf(fmaxf(v, 0.01f * v), ww.z, acy);
      v = (acc2[t][4 * rq + 3] - mu) * rr * gg.w + bb.w; acy = fmaf(fmaxf(v, 0.01f * v), ww.w, acy);
    }
  acy += __shfl_xor(acy, 32);
  if (hi == 0) out[e] = acy + bo3[0];
}

extern "C" void kernel_launch(void* const* d_in, const int* in_sizes, int n_in,
                              void* d_out, int out_size, void* d_ws, size_t ws_size,
                              hipStream_t stream) {
  const float* obs  = (const float*)d_in[0];
  const float* actn = (const float*)d_in[1];
  const int*   adj  = (const int*)d_in[2];
  const float* W1   = (const float*)d_in[3];
  const float* a1s  = (const float*)d_in[4];
  const float* a1d  = (const float*)d_in[5];
  const float* b1   = (const float*)d_in[6];
  const float* W2   = (const float*)d_in[7];
  const float* a2s  = (const float*)d_in[8];
  const float* a2d  = (const float*)d_in[9];
  const float* b2   = (const float*)d_in[10];
  const float* Wo1  = (const float*)d_in[11];
  const float* bo1  = (const float*)d_in[12];
  const float* g1   = (const float*)d_in[13];
  const float* be1  = (const float*)d_in[14];
  const float* Wo2  = (const float*)d_in[15];
  const float* bo2  = (const float*)d_in[16];
  const float* g2   = (const float*)d_in[17];
  const float* be2  = (const float*)d_in[18];
  const float* Wo3  = (const float*)d_in[19];
  const float* bo3  = (const float*)d_in[20];

  char* ws = (char*)d_ws;
  uint32_t* cntp = (uint32_t*)ws;                       // 1 MB
  uint16_t* W1F  = (uint16_t*)(ws + 1048576);           // 6144 B
  uint16_t* W2F  = (uint16_t*)(ws + 1048576 + 8192);    // 8192 B
  uint16_t* Wo1F = (uint16_t*)(ws + 1048576 + 16384);   // 98304 B
  uint16_t* Wo2F = (uint16_t*)(ws + 1048576 + 114688);  // 65536 B
  float*    wvec = (float*)(ws + 1048576 + 180224);     // 1024 B
  float* outp = (float*)d_out;

  prep_kernel<<<1024, 256, 0, stream>>>(adj, W1, a1s, a1d, W2, a2s, a2d, Wo1, Wo2,
                                        cntp, W1F, W2F, Wo1F, Wo2F, wvec);
  fused_kernel<<<2048, 256, 0, stream>>>(obs, actn, cntp, W1F, W2F, b1, b2,
                                         Wo1F, bo1, g1, be1, Wo2F, bo2, g2, be2,
                                         Wo3, bo3, wvec, outp);
}

// Round 10
// 118.146 us; speedup vs baseline: 3.2695x; 1.7793x over previous
//
#include <hip/hip_runtime.h>
#include <hip/hip_bf16.h>
#include <stdint.h>

#define B_TOT 262144

typedef __attribute__((ext_vector_type(8))) short bf8;
typedef __attribute__((ext_vector_type(16))) float f32x16;

__device__ __forceinline__ float bf2f(uint32_t u)   { return __uint_as_float(u << 16); }
__device__ __forceinline__ float bfhi2f(uint32_t u) { return __uint_as_float(u & 0xffff0000u); }
__device__ __forceinline__ uint32_t f2bf(float x) {
  uint32_t u = __float_as_uint(x);
  return (u + 0x7fffu + ((u >> 16) & 1u)) >> 16;   // RTN-even
}
__device__ __forceinline__ uint32_t pkbf(float lo, float hi) {
  union { __hip_bfloat162 b; uint32_t u; } c;
  c.b = __float22bfloat162_rn(make_float2(lo, hi));
  return c.u;
}
__device__ __forceinline__ bf8 mkfrag(uint32_t w0, uint32_t w1, uint32_t w2, uint32_t w3) {
  union { uint32_t u[4]; bf8 v; } c;
  c.u[0] = w0; c.u[1] = w1; c.u[2] = w2; c.u[3] = w3;
  return c.v;
}

// ---------------- prep: adj counts, W frags (true k-map), W@a score vectors ----------
// A/B frag k-mapping for mfma_32x32x16: lane l, elem e: k = 8*(e>>2)+4*(l>>5)+(e&3).
__global__ __launch_bounds__(256) void prep_kernel(
    const int* __restrict__ adj,
    const float* __restrict__ W1, const float* __restrict__ a1s, const float* __restrict__ a1d,
    const float* __restrict__ W2, const float* __restrict__ a2s, const float* __restrict__ a2d,
    const float* __restrict__ Wo1, const float* __restrict__ Wo2,
    uint32_t* __restrict__ cntp, uint16_t* __restrict__ W1F, uint16_t* __restrict__ W2F,
    uint16_t* __restrict__ Wo1F, uint16_t* __restrict__ Wo2F, float* __restrict__ wvec)
{
  const int gid = blockIdx.x * 256 + threadIdx.x;
  if (gid < B_TOT) {
    uint32_t cpv = 0;
    const int* ap = adj + (size_t)gid * 9;
    #pragma unroll
    for (int i = 0; i < 3; ++i)
      #pragma unroll
      for (int j = 0; j < 3; ++j) {
        uint32_t c = (uint32_t)ap[j * 3 + i] + (i == j ? 1u : 0u);  // adj^T + I
        cpv |= c << (2 * (3 * i + j));
      }
    cntp[gid] = cpv;
  }
  const int e = gid & 7, li = (gid >> 3) & 63;
  const int kfrag = 8 * (e >> 2) + 4 * (li >> 5) + (e & 3);
  if (gid < 3072) {   // W1^T frags [ks3][t2]
    const int f = gid >> 9, t = f & 1, ks = f >> 1;
    const int k = ks * 16 + kfrag, row = t * 32 + (li & 31);
    W1F[gid] = (uint16_t)f2bf(k < 35 ? W1[k * 64 + row] : 0.f);
  }
  if (gid < 4096) {   // W2^T frags [ks4][t2]
    const int f = gid >> 9, t = f & 1, ks = f >> 1;
    const int k = ks * 16 + kfrag, row = t * 32 + (li & 31);
    W2F[gid] = (uint16_t)f2bf(W2[k * 64 + row]);
  }
  if (gid < 49152) {  // Wo1^T frags [ks12][t8]
    const int rr = gid >> 9, t = rr & 7, ks = rr >> 3;
    const int k = ks * 16 + kfrag, col = t * 32 + (li & 31);
    Wo1F[gid] = (uint16_t)f2bf(Wo1[k * 256 + col]);
  }
  if (gid < 32768) {  // Wo2^T frags [ks16][t4]
    const int rr = gid >> 9, t = rr & 3, ks = rr >> 2;
    const int k = ks * 16 + kfrag, col = t * 32 + (li & 31);
    Wo2F[gid] = (uint16_t)f2bf(Wo2[k * 128 + col]);
  }
  if (gid < 224) {    // score vectors: [0..63]=W1@a1s (pad), [64..127]=W1@a1d, [128..191]=W2@a2s, [192..255]=W2@a2d
    if (gid < 48) {
      float s = 0.f; if (gid < 35) for (int d = 0; d < 64; ++d) s += W1[gid * 64 + d] * a1s[d];
      wvec[gid] = s;
    } else if (gid < 96) {
      const int k = gid - 48; float s = 0.f;
      if (k < 35) for (int d = 0; d < 64; ++d) s += W1[k * 64 + d] * a1d[d];
      wvec[64 + k] = s;
    } else if (gid < 160) {
      const int k = gid - 96; float s = 0.f;
      for (int d = 0; d < 64; ++d) s += W2[k * 64 + d] * a2s[d];
      wvec[128 + k] = s;
    } else {
      const int k = gid - 160; float s = 0.f;
      for (int d = 0; d < 64; ++d) s += W2[k * 64 + d] * a2d[d];
      wvec[192 + k] = s;
    }
  }
}

// --------- softmax helper: returns alpha[3][3] from reduced ss/sd + counts ----------
__device__ __forceinline__ void att_alpha(const float (&ss)[3], const float (&sd)[3],
                                          uint32_t cp, float (&al)[3][3])
{
  #pragma unroll
  for (int i = 0; i < 3; ++i) {
    float ev[3]; float mx = -1e30f;
    #pragma unroll
    for (int j = 0; j < 3; ++j) {
      float s = ss[j] + sd[i];
      s = fmaxf(s, 0.2f * s);              // leaky_relu 0.2
      ev[j] = s;
      int c = (cp >> (2 * (3 * i + j))) & 3;
      mx = fmaxf(mx, c ? s : -1e30f);
    }
    float sum = 0.f;
    #pragma unroll
    for (int j = 0; j < 3; ++j) {
      int c = (cp >> (2 * (3 * i + j))) & 3;
      float p = (float)c * __expf(ev[j] - mx);
      al[i][j] = p; sum += p;
    }
    float inv = 1.0f / sum;
    #pragma unroll
    for (int j = 0; j < 3; ++j) al[i][j] *= inv;
  }
}

// attention1: ELU + next-layer score dots; Ph to registers (reg-order pairwise pack)
__device__ __forceinline__ void attention1(const f32x16 (&az)[3][2],
    const float (&ss)[3], const float (&sd)[3], uint32_t cp, int hi,
    const float* __restrict__ bvec, const float* __restrict__ nxs, const float* __restrict__ nxd,
    uint32_t (&Ph)[3][16], float (&ss2)[3], float (&sd2)[3])
{
  float al[3][3];
  att_alpha(ss, sd, cp, al);
  #pragma unroll
  for (int t = 0; t < 2; ++t) {
    float bv[16], nsv[16], ndv[16];
    #pragma unroll
    for (int rq = 0; rq < 4; ++rq) {
      float4 b4 = *reinterpret_cast<const float4*>(bvec + t * 32 + rq * 8 + hi * 4);
      float4 s4 = *reinterpret_cast<const float4*>(nxs + t * 32 + rq * 8 + hi * 4);
      float4 d4 = *reinterpret_cast<const float4*>(nxd + t * 32 + rq * 8 + hi * 4);
      bv[4 * rq + 0] = b4.x; bv[4 * rq + 1] = b4.y; bv[4 * rq + 2] = b4.z; bv[4 * rq + 3] = b4.w;
      nsv[4 * rq + 0] = s4.x; nsv[4 * rq + 1] = s4.y; nsv[4 * rq + 2] = s4.z; nsv[4 * rq + 3] = s4.w;
      ndv[4 * rq + 0] = d4.x; ndv[4 * rq + 1] = d4.y; ndv[4 * rq + 2] = d4.z; ndv[4 * rq + 3] = d4.w;
    }
    #pragma unroll
    for (int i = 0; i < 3; ++i) {
      float hv[16];
      #pragma unroll
      for (int r = 0; r < 16; ++r) {
        float v = bv[r];
        v = fmaf(al[i][0], az[0][t][r], v);
        v = fmaf(al[i][1], az[1][t][r], v);
        v = fmaf(al[i][2], az[2][t][r], v);
        v = v > 0.f ? v : (__expf(v) - 1.f);          // ELU
        ss2[i] = fmaf(v, nsv[r], ss2[i]); sd2[i] = fmaf(v, ndv[r], sd2[i]);
        hv[r] = v;
      }
      #pragma unroll
      for (int p = 0; p < 8; ++p) Ph[i][t * 8 + p] = pkbf(hv[2 * p], hv[2 * p + 1]);
    }
  }
}

// attention2: no ELU; writes packed words straight to LDS column (stride 256 words)
__device__ __forceinline__ void attention2(const f32x16 (&az)[3][2],
    const float (&ss)[3], const float (&sd)[3], uint32_t cp, int hi,
    const float* __restrict__ bvec, uint32_t* __restrict__ ldscol)
{
  float al[3][3];
  att_alpha(ss, sd, cp, al);
  #pragma unroll
  for (int t = 0; t < 2; ++t) {
    float bv[16];
    #pragma unroll
    for (int rq = 0; rq < 4; ++rq) {
      float4 b4 = *reinterpret_cast<const float4*>(bvec + t * 32 + rq * 8 + hi * 4);
      bv[4 * rq + 0] = b4.x; bv[4 * rq + 1] = b4.y; bv[4 * rq + 2] = b4.z; bv[4 * rq + 3] = b4.w;
    }
    #pragma unroll
    for (int i = 0; i < 3; ++i) {
      float hv[16];
      #pragma unroll
      for (int r = 0; r < 16; ++r) {
        float v = bv[r];
        v = fmaf(al[i][0], az[0][t][r], v);
        v = fmaf(al[i][1], az[1][t][r], v);
        v = fmaf(al[i][2], az[2][t][r], v);
        hv[r] = v;
      }
      #pragma unroll
      for (int p = 0; p < 8; ++p)
        ldscol[(i * 16 + t * 8 + p) * 256] = pkbf(hv[2 * p], hv[2 * p + 1]);
    }
  }
}

// ---- fused: GAT per-wave (32 elems) -> block-cooperative MLP over 128 elems ----
// LDS word buffer [g][c]: index g*256 + c, c = hi*128 + elemInBlock. h2: g 0..47; y1: g 0..63.
// partials: LN1 at byte 49152 (inside g48..63, dead until y1); LN2/out at bytes 0..6143 (y1 dead).
__global__ __launch_bounds__(256, 2) void fused_kernel(
    const float* __restrict__ obs, const float* __restrict__ act,
    const uint32_t* __restrict__ cntp,
    const uint16_t* __restrict__ W1F, const uint16_t* __restrict__ W2F,
    const float* __restrict__ b1, const float* __restrict__ b2,
    const uint16_t* __restrict__ Wo1F, const float* __restrict__ bo1,
    const float* __restrict__ g1, const float* __restrict__ be1,
    const uint16_t* __restrict__ Wo2F, const float* __restrict__ bo2,
    const float* __restrict__ g2, const float* __restrict__ be2,
    const float* __restrict__ Wo3, const float* __restrict__ bo3,
    const float* __restrict__ wvec, float* __restrict__ out)
{
  __shared__ uint32_t buf[16384];   // 64 KB
  const int tid = threadIdx.x;
  const int l = tid & 63, hi = l >> 5, col = l & 31;
  const int w = tid >> 6;
  const int eb = w * 32 + col;                 // element within block (GAT ownership)
  const int e = blockIdx.x * 128 + eb;
  const uint32_t cp = cntp[e];
  const float* obs_e = obs + (size_t)e * 90;
  const float* act_e = act + (size_t)e * 15;

  // ===== GAT layer 1 (x split hi+lo bf16; per-lane f32 score dots) — R6 code =====
  f32x16 az[3][2];
  #pragma unroll
  for (int n = 0; n < 3; ++n)
    #pragma unroll
    for (int t = 0; t < 2; ++t)
      #pragma unroll
      for (int r = 0; r < 16; ++r) az[n][t][r] = 0.f;
  float ss1[3] = {0, 0, 0}, sd1[3] = {0, 0, 0};

  #pragma unroll
  for (int ks = 0; ks < 3; ++ks) {
    bf8 xh[3], xl[3];
    #pragma unroll
    for (int n = 0; n < 3; ++n) {
      const float* on = obs_e + n * 30;
      float xv[8];
      #pragma unroll
      for (int r2 = 0; r2 < 2; ++r2) {
        if (ks == 2 && r2 == 1) { xv[4] = xv[5] = xv[6] = xv[7] = 0.f; continue; }
        const int kb = ks * 16 + r2 * 8 + hi * 4;
        #pragma unroll
        for (int j = 0; j < 4; ++j) {
          const int k = kb + j;
          float v = 0.f;
          if (k < 30) v = on[k];
          else if (k < 35) v = act_e[n * 5 + (k - 30)];
          xv[r2 * 4 + j] = v;
        }
        float4 s4 = *reinterpret_cast<const float4*>(wvec + kb);
        float4 d4 = *reinterpret_cast<const float4*>(wvec + 64 + kb);
        ss1[n] = fmaf(xv[r2 * 4 + 0], s4.x, ss1[n]); sd1[n] = fmaf(xv[r2 * 4 + 0], d4.x, sd1[n]);
        ss1[n] = fmaf(xv[r2 * 4 + 1], s4.y, ss1[n]); sd1[n] = fmaf(xv[r2 * 4 + 1], d4.y, sd1[n]);
        ss1[n] = fmaf(xv[r2 * 4 + 2], s4.z, ss1[n]); sd1[n] = fmaf(xv[r2 * 4 + 2], d4.z, sd1[n]);
        ss1[n] = fmaf(xv[r2 * 4 + 3], s4.w, ss1[n]); sd1[n] = fmaf(xv[r2 * 4 + 3], d4.w, sd1[n]);
      }
      uint32_t hw[4], lw[4];
      #pragma unroll
      for (int p = 0; p < 4; ++p) {
        hw[p] = pkbf(xv[2 * p], xv[2 * p + 1]);
        float ra = xv[2 * p]     - bf2f(hw[p]);
        float rb = xv[2 * p + 1] - bfhi2f(hw[p]);
        lw[p] = (__float_as_uint(ra) >> 16) | (__float_as_uint(rb) & 0xffff0000u);
      }
      xh[n] = mkfrag(hw[0], hw[1], hw[2], hw[3]);
      xl[n] = mkfrag(lw[0], lw[1], lw[2], lw[3]);
    }
    #pragma unroll
    for (int t = 0; t < 2; ++t) {
      bf8 a = *reinterpret_cast<const bf8*>(W1F + (size_t)(ks * 2 + t) * 512 + l * 8);
      #pragma unroll
      for (int n = 0; n < 3; ++n) {
        az[n][t] = __builtin_amdgcn_mfma_f32_32x32x16_bf16(a, xh[n], az[n][t], 0, 0, 0);
        az[n][t] = __builtin_amdgcn_mfma_f32_32x32x16_bf16(a, xl[n], az[n][t], 0, 0, 0);
      }
    }
  }
  #pragma unroll
  for (int n = 0; n < 3; ++n) {
    ss1[n] += __shfl_xor(ss1[n], 32);
    sd1[n] += __shfl_xor(sd1[n], 32);
  }

  uint32_t Ph1[3][16];
  float ss2[3] = {0, 0, 0}, sd2[3] = {0, 0, 0};
  attention1(az, ss1, sd1, cp, hi, b1, wvec + 128, wvec + 192, Ph1, ss2, sd2);
  #pragma unroll
  for (int n = 0; n < 3; ++n) {
    ss2[n] += __shfl_xor(ss2[n], 32);
    sd2[n] += __shfl_xor(sd2[n], 32);
  }

  // ===== GAT layer 2 (Ph1 frags from regs) =====
  f32x16 a2[3][2];
  #pragma unroll
  for (int n = 0; n < 3; ++n)
    #pragma unroll
    for (int t = 0; t < 2; ++t)
      #pragma unroll
      for (int r = 0; r < 16; ++r) a2[n][t][r] = 0.f;
  #pragma unroll
  for (int ks = 0; ks < 4; ++ks) {
    #pragma unroll
    for (int t = 0; t < 2; ++t) {
      bf8 a = *reinterpret_cast<const bf8*>(W2F + (size_t)(ks * 2 + t) * 512 + l * 8);
      #pragma unroll
      for (int n = 0; n < 3; ++n) {
        bf8 br_ = mkfrag(Ph1[n][4 * ks], Ph1[n][4 * ks + 1], Ph1[n][4 * ks + 2], Ph1[n][4 * ks + 3]);
        a2[n][t] = __builtin_amdgcn_mfma_f32_32x32x16_bf16(a, br_, a2[n][t], 0, 0, 0);
      }
    }
  }

  // attention2 -> h2 packed words into LDS columns (g 0..47)
  attention2(a2, ss2, sd2, cp, hi, b2, buf + (hi * 128 + eb));
  __syncthreads();                                   // B1: h2 visible block-wide

  // ===== MLP1: wave w computes feats [64w,64w+64) for ALL 128 elems =====
  const int fb1 = w * 64;
  f32x16 acc[2][4];                                  // [t][eg] -> 128 f32
  #pragma unroll
  for (int t = 0; t < 2; ++t)
    #pragma unroll
    for (int rq = 0; rq < 4; ++rq) {
      float4 b4 = *reinterpret_cast<const float4*>(bo1 + fb1 + t * 32 + rq * 8 + hi * 4);
      #pragma unroll
      for (int eg = 0; eg < 4; ++eg) {
        acc[t][eg][4 * rq + 0] = b4.x; acc[t][eg][4 * rq + 1] = b4.y;
        acc[t][eg][4 * rq + 2] = b4.z; acc[t][eg][4 * rq + 3] = b4.w;
      }
    }
  #pragma unroll
  for (int ks = 0; ks < 12; ++ks) {
    bf8 bfr[4];
    #pragma unroll
    for (int eg = 0; eg < 4; ++eg) {
      const uint32_t* pc = buf + (hi * 128 + eg * 32 + col) + ks * 4 * 256;
      bfr[eg] = mkfrag(pc[0], pc[256], pc[512], pc[768]);
    }
    #pragma unroll
    for (int t = 0; t < 2; ++t) {
      bf8 a = *reinterpret_cast<const bf8*>(Wo1F + (size_t)(ks * 8 + w * 2 + t) * 512 + l * 8);
      #pragma unroll
      for (int eg = 0; eg < 4; ++eg)
        acc[t][eg] = __builtin_amdgcn_mfma_f32_32x32x16_bf16(a, bfr[eg], acc[t][eg], 0, 0, 0);
    }
  }
  // LN1 partials (wave's 64 feats per elem)
  {
    float psm[4], psq[4];
    #pragma unroll
    for (int eg = 0; eg < 4; ++eg) { psm[eg] = 0.f; psq[eg] = 0.f; }
    #pragma unroll
    for (int t = 0; t < 2; ++t)
      #pragma unroll
      for (int eg = 0; eg < 4; ++eg)
        #pragma unroll
        for (int r = 0; r < 16; ++r) {
          const float v = acc[t][eg][r]; psm[eg] += v; psq[eg] = fmaf(v, v, psq[eg]);
        }
    float* part = (float*)buf + 12288;               // bytes 49152.. (sm), +512 floats (sq)
    #pragma unroll
    for (int eg = 0; eg < 4; ++eg) {
      psm[eg] += __shfl_xor(psm[eg], 32);
      psq[eg] += __shfl_xor(psq[eg], 32);
      if (hi == 0) {
        part[w * 128 + eg * 32 + col] = psm[eg];
        part[512 + w * 128 + eg * 32 + col] = psq[eg];
      }
    }
  }
  __syncthreads();                                   // B2: partials visible
  float mu1[4], rr1[4];
  {
    const float* part = (const float*)buf + 12288;
    #pragma unroll
    for (int eg = 0; eg < 4; ++eg) {
      const int ei = eg * 32 + col;
      float s = part[ei] + part[128 + ei] + part[256 + ei] + part[384 + ei];
      float q = part[512 + ei] + part[640 + ei] + part[768 + ei] + part[896 + ei];
      mu1[eg] = s * (1.f / 256.f);
      rr1[eg] = rsqrtf(q * (1.f / 256.f) - mu1[eg] * mu1[eg] + 1e-5f);
    }
  }
  __syncthreads();                                   // B3: partial reads done; y1 may overwrite
  // LN1 apply + lrelu + pack -> y1 words (g = w*16 + t*8 + p)
  #pragma unroll
  for (int t = 0; t < 2; ++t)
    #pragma unroll
    for (int rq = 0; rq < 4; ++rq) {
      float4 gg = *reinterpret_cast<const float4*>(g1 + fb1 + t * 32 + rq * 8 + hi * 4);
      float4 bb = *reinterpret_cast<const float4*>(be1 + fb1 + t * 32 + rq * 8 + hi * 4);
      #pragma unroll
      for (int eg = 0; eg < 4; ++eg) {
        float v0 = (acc[t][eg][4 * rq + 0] - mu1[eg]) * rr1[eg] * gg.x + bb.x; v0 = fmaxf(v0, 0.01f * v0);
        float v1 = (acc[t][eg][4 * rq + 1] - mu1[eg]) * rr1[eg] * gg.y + bb.y; v1 = fmaxf(v1, 0.01f * v1);
        float v2 = (acc[t][eg][4 * rq + 2] - mu1[eg]) * rr1[eg] * gg.z + bb.z; v2 = fmaxf(v2, 0.01f * v2);
        float v3 = (acc[t][eg][4 * rq + 3] - mu1[eg]) * rr1[eg] * gg.w + bb.w; v3 = fmaxf(v3, 0.01f * v3);
        const int c = hi * 128 + eg * 32 + col;
        buf[(w * 16 + t * 8 + rq * 2 + 0) * 256 + c] = pkbf(v0, v1);
        buf[(w * 16 + t * 8 + rq * 2 + 1) * 256 + c] = pkbf(v2, v3);
      }
    }
  __syncthreads();                                   // B4: y1 complete

  // ===== MLP2: wave w computes feats [32w,32w+32) for ALL 128 elems =====
  const int fb2 = w * 32;
  f32x16 acc2[4];
  #pragma unroll
  for (int rq = 0; rq < 4; ++rq) {
    float4 b4 = *reinterpret_cast<const float4*>(bo2 + fb2 + rq * 8 + hi * 4);
    #pragma unroll
    for (int eg = 0; eg < 4; ++eg) {
      acc2[eg][4 * rq + 0] = b4.x; acc2[eg][4 * rq + 1] = b4.y;
      acc2[eg][4 * rq + 2] = b4.z; acc2[eg][4 * rq + 3] = b4.w;
    }
  }
  #pragma unroll
  for (int ks = 0; ks < 16; ++ks) {
    bf8 bfr[4];
    #pragma unroll
    for (int eg = 0; eg < 4; ++eg) {
      const uint32_t* pc = buf + (hi * 128 + eg * 32 + col) + ks * 4 * 256;
      bfr[eg] = mkfrag(pc[0], pc[256], pc[512], pc[768]);
    }
    bf8 a = *reinterpret_cast<const bf8*>(Wo2F + (size_t)(ks * 4 + w) * 512 + l * 8);
    #pragma unroll
    for (int eg = 0; eg < 4; ++eg)
      acc2[eg] = __builtin_amdgcn_mfma_f32_32x32x16_bf16(a, bfr[eg], acc2[eg], 0, 0, 0);
  }
  __syncthreads();                                   // B5: all y1 reads done
  // LN2 partials (wave's 32 feats per elem)
  {
    float psm[4], psq[4];
    #pragma unroll
    for (int eg = 0; eg < 4; ++eg) { psm[eg] = 0.f; psq[eg] = 0.f; }
    #pragma unroll
    for (int eg = 0; eg < 4; ++eg)
      #pragma unroll
      for (int r = 0; r < 16; ++r) {
        const float v = acc2[eg][r]; psm[eg] += v; psq[eg] = fmaf(v, v, psq[eg]);
      }
    float* part = (float*)buf;                       // sm [0..511], sq [512..1023]
    #pragma unroll
    for (int eg = 0; eg < 4; ++eg) {
      psm[eg] += __shfl_xor(psm[eg], 32);
      psq[eg] += __shfl_xor(psq[eg], 32);
      if (hi == 0) {
        part[w * 128 + eg * 32 + col] = psm[eg];
        part[512 + w * 128 + eg * 32 + col] = psq[eg];
      }
    }
  }
  __syncthreads();                                   // B6: LN2 partials visible
  {
    const float* part = (const float*)buf;
    float* p3 = (float*)buf + 1024;                  // dot partials [1024..1535]
    float dot[4];
    #pragma unroll
    for (int eg = 0; eg < 4; ++eg) {
      const int ei = eg * 32 + col;
      float s = part[ei] + part[128 + ei] + part[256 + ei] + part[384 + ei];
      float q = part[512 + ei] + part[640 + ei] + part[768 + ei] + part[896 + ei];
      const float mu = s * (1.f / 128.f);
      const float rr = rsqrtf(q * (1.f / 128.f) - mu * mu + 1e-5f);
      float d = 0.f;
      #pragma unroll
      for (int rq = 0; rq < 4; ++rq) {
        float4 gg = *reinterpret_cast<const float4*>(g2 + fb2 + rq * 8 + hi * 4);
        float4 bb = *reinterpret_cast<const float4*>(be2 + fb2 + rq * 8 + hi * 4);
        float4 ww = *reinterpret_cast<const float4*>(Wo3 + fb2 + rq * 8 + hi * 4);
        float v;
        v = (acc2[eg][4 * rq + 0] - mu) * rr * gg.x + bb.x; d = fmaf(fmaxf(v, 0.01f * v), ww.x, d);
        v = (acc2[eg][4 * rq + 1] - mu) * rr * gg.y + bb.y; d = fmaf(fmaxf(v, 0.01f * v), ww.y, d);
        v = (acc2[eg][4 * rq + 2] - mu) * rr * gg.z + bb.z; d = fmaf(fmaxf(v, 0.01f * v), ww.z, d);
        v = (acc2[eg][4 * rq + 3] - mu) * rr * gg.w + bb.w; d = fmaf(fmaxf(v, 0.01f * v), ww.w, d);
      }
      dot[eg] = d;
    }
    #pragma unroll
    for (int eg = 0; eg < 4; ++eg) {
      dot[eg] += __shfl_xor(dot[eg], 32);
      if (hi == 0) p3[w * 128 + eg * 32 + col] = dot[eg];
    }
  }
  __syncthreads();                                   // B7: dot partials visible
  if (tid < 128) {
    const float* p3 = (const float*)buf + 1024;
    out[blockIdx.x * 128 + tid] =
        p3[tid] + p3[128 + tid] + p3[256 + tid] + p3[384 + tid] + bo3[0];
  }
}

extern "C" void kernel_launch(void* const* d_in, const int* in_sizes, int n_in,
                              void* d_out, int out_size, void* d_ws, size_t ws_size,
                              hipStream_t stream) {
  const float* obs  = (const float*)d_in[0];
  const float* actn = (const float*)d_in[1];
  const int*   adj  = (const int*)d_in[2];
  const float* W1   = (const float*)d_in[3];
  const float* a1s  = (const float*)d_in[4];
  const float* a1d  = (const float*)d_in[5];
  const float* b1   = (const float*)d_in[6];
  const float* W2   = (const float*)d_in[7];
  const float* a2s  = (const float*)d_in[8];
  const float* a2d  = (const float*)d_in[9];
  const float* b2   = (const float*)d_in[10];
  const float* Wo1  = (const float*)d_in[11];
  const float* bo1  = (const float*)d_in[12];
  const float* g1   = (const float*)d_in[13];
  const float* be1  = (const float*)d_in[14];
  const float* Wo2  = (const float*)d_in[15];
  const float* bo2  = (const float*)d_in[16];
  const float* g2   = (const float*)d_in[17];
  const float* be2  = (const float*)d_in[18];
  const float* Wo3  = (const float*)d_in[19];
  const float* bo3  = (const float*)d_in[20];

  char* ws = (char*)d_ws;
  uint32_t* cntp = (uint32_t*)ws;                       // 1 MB
  uint16_t* W1F  = (uint16_t*)(ws + 1048576);           // 6144 B
  uint16_t* W2F  = (uint16_t*)(ws + 1048576 + 8192);    // 8192 B
  uint16_t* Wo1F = (uint16_t*)(ws + 1048576 + 16384);   // 98304 B
  uint16_t* Wo2F = (uint16_t*)(ws + 1048576 + 114688);  // 65536 B
  float*    wvec = (float*)(ws + 1048576 + 180224);     // 1024 B
  float* outp = (float*)d_out;

  prep_kernel<<<1024, 256, 0, stream>>>(adj, W1, a1s, a1d, W2, a2s, a2d, Wo1, Wo2,
                                        cntp, W1F, W2F, Wo1F, Wo2F, wvec);
  fused_kernel<<<2048, 256, 0, stream>>>(obs, actn, cntp, W1F, W2F, b1, b2,
                                         Wo1F, bo1, g1, be1, Wo2F, bo2, g2, be2,
                                         Wo3, bo3, wvec, outp);
}

// Round 11
// 113.978 us; speedup vs baseline: 3.3890x; 1.0366x over previous
//
#include <hip/hip_runtime.h>
#include <hip/hip_bf16.h>
#include <stdint.h>

#define B_TOT 262144

typedef __attribute__((ext_vector_type(8))) short bf8;
typedef __attribute__((ext_vector_type(16))) float f32x16;

__device__ __forceinline__ float bf2f(uint32_t u)   { return __uint_as_float(u << 16); }
__device__ __forceinline__ float bfhi2f(uint32_t u) { return __uint_as_float(u & 0xffff0000u); }
__device__ __forceinline__ uint32_t f2bf(float x) {
  uint32_t u = __float_as_uint(x);
  return (u + 0x7fffu + ((u >> 16) & 1u)) >> 16;   // RTN-even
}
__device__ __forceinline__ uint32_t pkbf(float lo, float hi) {
  union { __hip_bfloat162 b; uint32_t u; } c;
  c.b = __float22bfloat162_rn(make_float2(lo, hi));
  return c.u;
}
__device__ __forceinline__ bf8 mkfrag(uint32_t w0, uint32_t w1, uint32_t w2, uint32_t w3) {
  union { uint32_t u[4]; bf8 v; } c;
  c.u[0] = w0; c.u[1] = w1; c.u[2] = w2; c.u[3] = w3;
  return c.v;
}
__device__ __forceinline__ bf8 u4bf8(uint4 v) {
  union { uint4 u; bf8 b; } c; c.u = v; return c.b;
}
// swizzled uint4 index for (column c, 16B-group q): spreads groups across banks
__device__ __forceinline__ int swz(int c, int q) { return c * 16 + (q ^ (c & 15)); }

// ---------------- prep: adj counts, W frags (true k-map), W@a score vectors ----------
// A/B frag k-mapping for mfma_32x32x16: lane l, elem e: k = 8*(e>>2)+4*(l>>5)+(e&3).
__global__ __launch_bounds__(256) void prep_kernel(
    const int* __restrict__ adj,
    const float* __restrict__ W1, const float* __restrict__ a1s, const float* __restrict__ a1d,
    const float* __restrict__ W2, const float* __restrict__ a2s, const float* __restrict__ a2d,
    const float* __restrict__ Wo1, const float* __restrict__ Wo2,
    uint32_t* __restrict__ cntp, uint16_t* __restrict__ W1F, uint16_t* __restrict__ W2F,
    uint16_t* __restrict__ Wo1F, uint16_t* __restrict__ Wo2F, float* __restrict__ wvec)
{
  const int gid = blockIdx.x * 256 + threadIdx.x;
  if (gid < B_TOT) {
    uint32_t cpv = 0;
    const int* ap = adj + (size_t)gid * 9;
    #pragma unroll
    for (int i = 0; i < 3; ++i)
      #pragma unroll
      for (int j = 0; j < 3; ++j) {
        uint32_t c = (uint32_t)ap[j * 3 + i] + (i == j ? 1u : 0u);  // adj^T + I
        cpv |= c << (2 * (3 * i + j));
      }
    cntp[gid] = cpv;
  }
  const int e = gid & 7, li = (gid >> 3) & 63;
  const int kfrag = 8 * (e >> 2) + 4 * (li >> 5) + (e & 3);
  if (gid < 3072) {   // W1^T frags [ks3][t2]
    const int f = gid >> 9, t = f & 1, ks = f >> 1;
    const int k = ks * 16 + kfrag, row = t * 32 + (li & 31);
    W1F[gid] = (uint16_t)f2bf(k < 35 ? W1[k * 64 + row] : 0.f);
  }
  if (gid < 4096) {   // W2^T frags [ks4][t2]
    const int f = gid >> 9, t = f & 1, ks = f >> 1;
    const int k = ks * 16 + kfrag, row = t * 32 + (li & 31);
    W2F[gid] = (uint16_t)f2bf(W2[k * 64 + row]);
  }
  if (gid < 49152) {  // Wo1^T frags [ks12][t8]
    const int rr = gid >> 9, t = rr & 7, ks = rr >> 3;
    const int k = ks * 16 + kfrag, col = t * 32 + (li & 31);
    Wo1F[gid] = (uint16_t)f2bf(Wo1[k * 256 + col]);
  }
  if (gid < 32768) {  // Wo2^T frags [ks16][t4]
    const int rr = gid >> 9, t = rr & 3, ks = rr >> 2;
    const int k = ks * 16 + kfrag, col = t * 32 + (li & 31);
    Wo2F[gid] = (uint16_t)f2bf(Wo2[k * 128 + col]);
  }
  if (gid < 224) {    // score vectors: [0..63]=W1@a1s (pad), [64..127]=W1@a1d, [128..191]=W2@a2s, [192..255]=W2@a2d
    if (gid < 48) {
      float s = 0.f; if (gid < 35) for (int d = 0; d < 64; ++d) s += W1[gid * 64 + d] * a1s[d];
      wvec[gid] = s;
    } else if (gid < 96) {
      const int k = gid - 48; float s = 0.f;
      if (k < 35) for (int d = 0; d < 64; ++d) s += W1[k * 64 + d] * a1d[d];
      wvec[64 + k] = s;
    } else if (gid < 160) {
      const int k = gid - 96; float s = 0.f;
      for (int d = 0; d < 64; ++d) s += W2[k * 64 + d] * a2s[d];
      wvec[128 + k] = s;
    } else {
      const int k = gid - 160; float s = 0.f;
      for (int d = 0; d < 64; ++d) s += W2[k * 64 + d] * a2d[d];
      wvec[192 + k] = s;
    }
  }
}

// --------- softmax helper: returns alpha[3][3] from reduced ss/sd + counts ----------
__device__ __forceinline__ void att_alpha(const float (&ss)[3], const float (&sd)[3],
                                          uint32_t cp, float (&al)[3][3])
{
  #pragma unroll
  for (int i = 0; i < 3; ++i) {
    float ev[3]; float mx = -1e30f;
    #pragma unroll
    for (int j = 0; j < 3; ++j) {
      float s = ss[j] + sd[i];
      s = fmaxf(s, 0.2f * s);              // leaky_relu 0.2
      ev[j] = s;
      int c = (cp >> (2 * (3 * i + j))) & 3;
      mx = fmaxf(mx, c ? s : -1e30f);
    }
    float sum = 0.f;
    #pragma unroll
    for (int j = 0; j < 3; ++j) {
      int c = (cp >> (2 * (3 * i + j))) & 3;
      float p = (float)c * __expf(ev[j] - mx);
      al[i][j] = p; sum += p;
    }
    float inv = 1.0f / sum;
    #pragma unroll
    for (int j = 0; j < 3; ++j) al[i][j] *= inv;
  }
}

// attention1: ELU + next-layer score dots; Ph to registers (reg-order pairwise pack)
__device__ __forceinline__ void attention1(const f32x16 (&az)[3][2],
    const float (&ss)[3], const float (&sd)[3], uint32_t cp, int hi,
    const float* __restrict__ bvec, const float* __restrict__ nxs, const float* __restrict__ nxd,
    uint32_t (&Ph)[3][16], float (&ss2)[3], float (&sd2)[3])
{
  float al[3][3];
  att_alpha(ss, sd, cp, al);
  #pragma unroll
  for (int t = 0; t < 2; ++t) {
    float bv[16], nsv[16], ndv[16];
    #pragma unroll
    for (int rq = 0; rq < 4; ++rq) {
      float4 b4 = *reinterpret_cast<const float4*>(bvec + t * 32 + rq * 8 + hi * 4);
      float4 s4 = *reinterpret_cast<const float4*>(nxs + t * 32 + rq * 8 + hi * 4);
      float4 d4 = *reinterpret_cast<const float4*>(nxd + t * 32 + rq * 8 + hi * 4);
      bv[4 * rq + 0] = b4.x; bv[4 * rq + 1] = b4.y; bv[4 * rq + 2] = b4.z; bv[4 * rq + 3] = b4.w;
      nsv[4 * rq + 0] = s4.x; nsv[4 * rq + 1] = s4.y; nsv[4 * rq + 2] = s4.z; nsv[4 * rq + 3] = s4.w;
      ndv[4 * rq + 0] = d4.x; ndv[4 * rq + 1] = d4.y; ndv[4 * rq + 2] = d4.z; ndv[4 * rq + 3] = d4.w;
    }
    #pragma unroll
    for (int i = 0; i < 3; ++i) {
      float hv[16];
      #pragma unroll
      for (int r = 0; r < 16; ++r) {
        float v = bv[r];
        v = fmaf(al[i][0], az[0][t][r], v);
        v = fmaf(al[i][1], az[1][t][r], v);
        v = fmaf(al[i][2], az[2][t][r], v);
        v = v > 0.f ? v : (__expf(v) - 1.f);          // ELU
        ss2[i] = fmaf(v, nsv[r], ss2[i]); sd2[i] = fmaf(v, ndv[r], sd2[i]);
        hv[r] = v;
      }
      #pragma unroll
      for (int p = 0; p < 8; ++p) Ph[i][t * 8 + p] = pkbf(hv[2 * p], hv[2 * p + 1]);
    }
  }
}

// attention2: no ELU; packs h2 and writes 2 x b128 per (i,t) to the swizzled column
__device__ __forceinline__ void attention2(const f32x16 (&az)[3][2],
    const float (&ss)[3], const float (&sd)[3], uint32_t cp, int hi,
    const float* __restrict__ bvec, uint4* __restrict__ b4p, int c_own)
{
  float al[3][3];
  att_alpha(ss, sd, cp, al);
  #pragma unroll
  for (int t = 0; t < 2; ++t) {
    float bv[16];
    #pragma unroll
    for (int rq = 0; rq < 4; ++rq) {
      float4 b4 = *reinterpret_cast<const float4*>(bvec + t * 32 + rq * 8 + hi * 4);
      bv[4 * rq + 0] = b4.x; bv[4 * rq + 1] = b4.y; bv[4 * rq + 2] = b4.z; bv[4 * rq + 3] = b4.w;
    }
    #pragma unroll
    for (int i = 0; i < 3; ++i) {
      float hv[16];
      #pragma unroll
      for (int r = 0; r < 16; ++r) {
        float v = bv[r];
        v = fmaf(al[i][0], az[0][t][r], v);
        v = fmaf(al[i][1], az[1][t][r], v);
        v = fmaf(al[i][2], az[2][t][r], v);
        hv[r] = v;
      }
      uint32_t w0 = pkbf(hv[0], hv[1]),  w1 = pkbf(hv[2], hv[3]);
      uint32_t w2 = pkbf(hv[4], hv[5]),  w3 = pkbf(hv[6], hv[7]);
      uint32_t w4 = pkbf(hv[8], hv[9]),  w5 = pkbf(hv[10], hv[11]);
      uint32_t w6 = pkbf(hv[12], hv[13]), w7 = pkbf(hv[14], hv[15]);
      b4p[swz(c_own, i * 4 + t * 2 + 0)] = make_uint4(w0, w1, w2, w3);
      b4p[swz(c_own, i * 4 + t * 2 + 1)] = make_uint4(w4, w5, w6, w7);
    }
  }
}

// ---- fused: GAT per-wave (32 elems) -> block-cooperative MLP; column-major swizzled LDS
__global__ __launch_bounds__(256, 2) void fused_kernel(
    const float* __restrict__ obs, const float* __restrict__ act,
    const uint32_t* __restrict__ cntp,
    const uint16_t* __restrict__ W1F, const uint16_t* __restrict__ W2F,
    const float* __restrict__ b1, const float* __restrict__ b2,
    const uint16_t* __restrict__ Wo1F, const float* __restrict__ bo1,
    const float* __restrict__ g1, const float* __restrict__ be1,
    const uint16_t* __restrict__ Wo2F, const float* __restrict__ bo2,
    const float* __restrict__ g2, const float* __restrict__ be2,
    const float* __restrict__ Wo3, const float* __restrict__ bo3,
    const float* __restrict__ wvec, float* __restrict__ out)
{
  __shared__ __align__(16) uint32_t buf[16384];   // 64 KB: 256 columns x 64 words (swizzled)
  __shared__ float part[1536];                    // 6 KB: LN partials + output partials
  uint4* b4p = (uint4*)buf;
  const uint4* b4c = (const uint4*)buf;
  const int tid = threadIdx.x;
  const int l = tid & 63, hi = l >> 5, col = l & 31;
  const int w = tid >> 6;
  const int eb = w * 32 + col;                 // element within block (GAT ownership)
  const int e = blockIdx.x * 128 + eb;
  const uint32_t cp = cntp[e];
  const float* obs_e = obs + (size_t)e * 90;
  const float* act_e = act + (size_t)e * 15;

  // ===== GAT layer 1 (x as single bf16; per-lane f32 score dots) =====
  f32x16 az[3][2];
  #pragma unroll
  for (int n = 0; n < 3; ++n)
    #pragma unroll
    for (int t = 0; t < 2; ++t)
      #pragma unroll
      for (int r = 0; r < 16; ++r) az[n][t][r] = 0.f;
  float ss1[3] = {0, 0, 0}, sd1[3] = {0, 0, 0};

  #pragma unroll
  for (int ks = 0; ks < 3; ++ks) {
    bf8 xh[3];
    #pragma unroll
    for (int n = 0; n < 3; ++n) {
      const float* on = obs_e + n * 30;
      float xv[8];
      #pragma unroll
      for (int r2 = 0; r2 < 2; ++r2) {
        if (ks == 2 && r2 == 1) { xv[4] = xv[5] = xv[6] = xv[7] = 0.f; continue; }
        const int kb = ks * 16 + r2 * 8 + hi * 4;
        #pragma unroll
        for (int j = 0; j < 4; ++j) {
          const int k = kb + j;
          float v = 0.f;
          if (k < 30) v = on[k];
          else if (k < 35) v = act_e[n * 5 + (k - 30)];
          xv[r2 * 4 + j] = v;
        }
        float4 s4 = *reinterpret_cast<const float4*>(wvec + kb);
        float4 d4 = *reinterpret_cast<const float4*>(wvec + 64 + kb);
        ss1[n] = fmaf(xv[r2 * 4 + 0], s4.x, ss1[n]); sd1[n] = fmaf(xv[r2 * 4 + 0], d4.x, sd1[n]);
        ss1[n] = fmaf(xv[r2 * 4 + 1], s4.y, ss1[n]); sd1[n] = fmaf(xv[r2 * 4 + 1], d4.y, sd1[n]);
        ss1[n] = fmaf(xv[r2 * 4 + 2], s4.z, ss1[n]); sd1[n] = fmaf(xv[r2 * 4 + 2], d4.z, sd1[n]);
        ss1[n] = fmaf(xv[r2 * 4 + 3], s4.w, ss1[n]); sd1[n] = fmaf(xv[r2 * 4 + 3], d4.w, sd1[n]);
      }
      xh[n] = mkfrag(pkbf(xv[0], xv[1]), pkbf(xv[2], xv[3]),
                     pkbf(xv[4], xv[5]), pkbf(xv[6], xv[7]));
    }
    #pragma unroll
    for (int t = 0; t < 2; ++t) {
      bf8 a = *reinterpret_cast<const bf8*>(W1F + (size_t)(ks * 2 + t) * 512 + l * 8);
      #pragma unroll
      for (int n = 0; n < 3; ++n)
        az[n][t] = __builtin_amdgcn_mfma_f32_32x32x16_bf16(a, xh[n], az[n][t], 0, 0, 0);
    }
  }
  #pragma unroll
  for (int n = 0; n < 3; ++n) {
    ss1[n] += __shfl_xor(ss1[n], 32);
    sd1[n] += __shfl_xor(sd1[n], 32);
  }

  uint32_t Ph1[3][16];
  float ss2[3] = {0, 0, 0}, sd2[3] = {0, 0, 0};
  attention1(az, ss1, sd1, cp, hi, b1, wvec + 128, wvec + 192, Ph1, ss2, sd2);
  #pragma unroll
  for (int n = 0; n < 3; ++n) {
    ss2[n] += __shfl_xor(ss2[n], 32);
    sd2[n] += __shfl_xor(sd2[n], 32);
  }

  // ===== GAT layer 2 (Ph1 frags from regs) =====
  f32x16 a2[3][2];
  #pragma unroll
  for (int n = 0; n < 3; ++n)
    #pragma unroll
    for (int t = 0; t < 2; ++t)
      #pragma unroll
      for (int r = 0; r < 16; ++r) a2[n][t][r] = 0.f;
  #pragma unroll
  for (int ks = 0; ks < 4; ++ks) {
    #pragma unroll
    for (int t = 0; t < 2; ++t) {
      bf8 a = *reinterpret_cast<const bf8*>(W2F + (size_t)(ks * 2 + t) * 512 + l * 8);
      #pragma unroll
      for (int n = 0; n < 3; ++n) {
        bf8 br_ = mkfrag(Ph1[n][4 * ks], Ph1[n][4 * ks + 1], Ph1[n][4 * ks + 2], Ph1[n][4 * ks + 3]);
        a2[n][t] = __builtin_amdgcn_mfma_f32_32x32x16_bf16(a, br_, a2[n][t], 0, 0, 0);
      }
    }
  }

  // attention2 -> h2 packed into swizzled column (groups 0..11)
  attention2(a2, ss2, sd2, cp, hi, b2, b4p, hi * 128 + eb);
  __syncthreads();                                   // B1: h2 visible block-wide

  // ===== MLP1: wave w computes feats [64w,64w+64) for ALL 128 elems =====
  const int fb1 = w * 64;
  f32x16 acc[2][4];                                  // [t][eg]
  #pragma unroll
  for (int t = 0; t < 2; ++t)
    #pragma unroll
    for (int rq = 0; rq < 4; ++rq) {
      float4 b4 = *reinterpret_cast<const float4*>(bo1 + fb1 + t * 32 + rq * 8 + hi * 4);
      #pragma unroll
      for (int eg = 0; eg < 4; ++eg) {
        acc[t][eg][4 * rq + 0] = b4.x; acc[t][eg][4 * rq + 1] = b4.y;
        acc[t][eg][4 * rq + 2] = b4.z; acc[t][eg][4 * rq + 3] = b4.w;
      }
    }
  #pragma unroll
  for (int ks = 0; ks < 12; ++ks) {
    bf8 bfr[4];
    #pragma unroll
    for (int eg = 0; eg < 4; ++eg)
      bfr[eg] = u4bf8(b4c[swz(hi * 128 + eg * 32 + col, ks)]);
    #pragma unroll
    for (int t = 0; t < 2; ++t) {
      bf8 a = *reinterpret_cast<const bf8*>(Wo1F + (size_t)(ks * 8 + w * 2 + t) * 512 + l * 8);
      #pragma unroll
      for (int eg = 0; eg < 4; ++eg)
        acc[t][eg] = __builtin_amdgcn_mfma_f32_32x32x16_bf16(a, bfr[eg], acc[t][eg], 0, 0, 0);
    }
  }
  // LN1 partials (wave's 64 feats per elem)
  {
    float psm[4], psq[4];
    #pragma unroll
    for (int eg = 0; eg < 4; ++eg) { psm[eg] = 0.f; psq[eg] = 0.f; }
    #pragma unroll
    for (int t = 0; t < 2; ++t)
      #pragma unroll
      for (int eg = 0; eg < 4; ++eg)
        #pragma unroll
        for (int r = 0; r < 16; ++r) {
          const float v = acc[t][eg][r]; psm[eg] += v; psq[eg] = fmaf(v, v, psq[eg]);
        }
    #pragma unroll
    for (int eg = 0; eg < 4; ++eg) {
      psm[eg] += __shfl_xor(psm[eg], 32);
      psq[eg] += __shfl_xor(psq[eg], 32);
      if (hi == 0) {
        part[w * 128 + eg * 32 + col] = psm[eg];
        part[512 + w * 128 + eg * 32 + col] = psq[eg];
      }
    }
  }
  __syncthreads();                                   // B2: LN1 partials visible; h reads done
  float mu1[4], rr1[4];
  #pragma unroll
  for (int eg = 0; eg < 4; ++eg) {
    const int ei = eg * 32 + col;
    float s = part[ei] + part[128 + ei] + part[256 + ei] + part[384 + ei];
    float q = part[512 + ei] + part[640 + ei] + part[768 + ei] + part[896 + ei];
    mu1[eg] = s * (1.f / 256.f);
    rr1[eg] = rsqrtf(q * (1.f / 256.f) - mu1[eg] * mu1[eg] + 1e-5f);
  }
  // LN1 apply + lrelu + pack -> y1 b128 writes (groups w*4+t*2, +1); overwrites h (dead)
  #pragma unroll
  for (int t = 0; t < 2; ++t) {
    float gv[16], bv[16];
    #pragma unroll
    for (int rq = 0; rq < 4; ++rq) {
      float4 gg = *reinterpret_cast<const float4*>(g1 + fb1 + t * 32 + rq * 8 + hi * 4);
      float4 bb = *reinterpret_cast<const float4*>(be1 + fb1 + t * 32 + rq * 8 + hi * 4);
      gv[4 * rq + 0] = gg.x; gv[4 * rq + 1] = gg.y; gv[4 * rq + 2] = gg.z; gv[4 * rq + 3] = gg.w;
      bv[4 * rq + 0] = bb.x; bv[4 * rq + 1] = bb.y; bv[4 * rq + 2] = bb.z; bv[4 * rq + 3] = bb.w;
    }
    #pragma unroll
    for (int eg = 0; eg < 4; ++eg) {
      uint32_t wd[8];
      #pragma unroll
      for (int p = 0; p < 8; ++p) {
        float va = (acc[t][eg][2 * p]     - mu1[eg]) * rr1[eg] * gv[2 * p]     + bv[2 * p];
        float vb = (acc[t][eg][2 * p + 1] - mu1[eg]) * rr1[eg] * gv[2 * p + 1] + bv[2 * p + 1];
        va = fmaxf(va, 0.01f * va);
        vb = fmaxf(vb, 0.01f * vb);
        wd[p] = pkbf(va, vb);
      }
      const int c = hi * 128 + eg * 32 + col;
      b4p[swz(c, w * 4 + t * 2 + 0)] = make_uint4(wd[0], wd[1], wd[2], wd[3]);
      b4p[swz(c, w * 4 + t * 2 + 1)] = make_uint4(wd[4], wd[5], wd[6], wd[7]);
    }
  }
  __syncthreads();                                   // B4: y1 complete

  // ===== MLP2: wave w computes feats [32w,32w+32) for ALL 128 elems =====
  const int fb2 = w * 32;
  f32x16 acc2[4];
  #pragma unroll
  for (int rq = 0; rq < 4; ++rq) {
    float4 b4 = *reinterpret_cast<const float4*>(bo2 + fb2 + rq * 8 + hi * 4);
    #pragma unroll
    for (int eg = 0; eg < 4; ++eg) {
      acc2[eg][4 * rq + 0] = b4.x; acc2[eg][4 * rq + 1] = b4.y;
      acc2[eg][4 * rq + 2] = b4.z; acc2[eg][4 * rq + 3] = b4.w;
    }
  }
  #pragma unroll
  for (int ks = 0; ks < 16; ++ks) {
    bf8 bfr[4];
    #pragma unroll
    for (int eg = 0; eg < 4; ++eg)
      bfr[eg] = u4bf8(b4c[swz(hi * 128 + eg * 32 + col, ks)]);
    bf8 a = *reinterpret_cast<const bf8*>(Wo2F + (size_t)(ks * 4 + w) * 512 + l * 8);
    #pragma unroll
    for (int eg = 0; eg < 4; ++eg)
      acc2[eg] = __builtin_amdgcn_mfma_f32_32x32x16_bf16(a, bfr[eg], acc2[eg], 0, 0, 0);
  }
  // LN2 partials (wave's 32 feats per elem)
  {
    float psm[4], psq[4];
    #pragma unroll
    for (int eg = 0; eg < 4; ++eg) { psm[eg] = 0.f; psq[eg] = 0.f; }
    #pragma unroll
    for (int eg = 0; eg < 4; ++eg)
      #pragma unroll
      for (int r = 0; r < 16; ++r) {
        const float v = acc2[eg][r]; psm[eg] += v; psq[eg] = fmaf(v, v, psq[eg]);
      }
    #pragma unroll
    for (int eg = 0; eg < 4; ++eg) {
      psm[eg] += __shfl_xor(psm[eg], 32);
      psq[eg] += __shfl_xor(psq[eg], 32);
      if (hi == 0) {
        part[w * 128 + eg * 32 + col] = psm[eg];
        part[512 + w * 128 + eg * 32 + col] = psq[eg];
      }
    }
  }
  __syncthreads();                                   // B6: LN2 partials visible
  {
    float dot[4];
    #pragma unroll
    for (int eg = 0; eg < 4; ++eg) {
      const int ei = eg * 32 + col;
      float s = part[ei] + part[128 + ei] + part[256 + ei] + part[384 + ei];
      float q = part[512 + ei] + part[640 + ei] + part[768 + ei] + part[896 + ei];
      const float mu = s * (1.f / 128.f);
      const float rr = rsqrtf(q * (1.f / 128.f) - mu * mu + 1e-5f);
      float d = 0.f;
      #pragma unroll
      for (int rq = 0; rq < 4; ++rq) {
        float4 gg = *reinterpret_cast<const float4*>(g2 + fb2 + rq * 8 + hi * 4);
        float4 bb = *reinterpret_cast<const float4*>(be2 + fb2 + rq * 8 + hi * 4);
        float4 ww = *reinterpret_cast<const float4*>(Wo3 + fb2 + rq * 8 + hi * 4);
        float v;
        v = (acc2[eg][4 * rq + 0] - mu) * rr * gg.x + bb.x; d = fmaf(fmaxf(v, 0.01f * v), ww.x, d);
        v = (acc2[eg][4 * rq + 1] - mu) * rr * gg.y + bb.y; d = fmaf(fmaxf(v, 0.01f * v), ww.y, d);
        v = (acc2[eg][4 * rq + 2] - mu) * rr * gg.z + bb.z; d = fmaf(fmaxf(v, 0.01f * v), ww.z, d);
        v = (acc2[eg][4 * rq + 3] - mu) * rr * gg.w + bb.w; d = fmaf(fmaxf(v, 0.01f * v), ww.w, d);
      }
      dot[eg] = d;
    }
    #pragma unroll
    for (int eg = 0; eg < 4; ++eg) {
      dot[eg] += __shfl_xor(dot[eg], 32);
      if (hi == 0) part[1024 + w * 128 + eg * 32 + col] = dot[eg];
    }
  }
  __syncthreads();                                   // B7: dot partials visible
  if (tid < 128) {
    out[blockIdx.x * 128 + tid] = part[1024 + tid] + part[1152 + tid] +
                                  part[1280 + tid] + part[1408 + tid] + bo3[0];
  }
}

extern "C" void kernel_launch(void* const* d_in, const int* in_sizes, int n_in,
                              void* d_out, int out_size, void* d_ws, size_t ws_size,
                              hipStream_t stream) {
  const float* obs  = (const float*)d_in[0];
  const float* actn = (const float*)d_in[1];
  const int*   adj  = (const int*)d_in[2];
  const float* W1   = (const float*)d_in[3];
  const float* a1s  = (const float*)d_in[4];
  const float* a1d  = (const float*)d_in[5];
  const float* b1   = (const float*)d_in[6];
  const float* W2   = (const float*)d_in[7];
  const float* a2s  = (const float*)d_in[8];
  const float* a2d  = (const float*)d_in[9];
  const float* b2   = (const float*)d_in[10];
  const float* Wo1  = (const float*)d_in[11];
  const float* bo1  = (const float*)d_in[12];
  const float* g1   = (const float*)d_in[13];
  const float* be1  = (const float*)d_in[14];
  const float* Wo2  = (const float*)d_in[15];
  const float* bo2  = (const float*)d_in[16];
  const float* g2   = (const float*)d_in[17];
  const float* be2  = (const float*)d_in[18];
  const float* Wo3  = (const float*)d_in[19];
  const float* bo3  = (const float*)d_in[20];

  char* ws = (char*)d_ws;
  uint32_t* cntp = (uint32_t*)ws;                       // 1 MB
  uint16_t* W1F  = (uint16_t*)(ws + 1048576);           // 6144 B
  uint16_t* W2F  = (uint16_t*)(ws + 1048576 + 8192);    // 8192 B
  uint16_t* Wo1F = (uint16_t*)(ws + 1048576 + 16384);   // 98304 B
  uint16_t* Wo2F = (uint16_t*)(ws + 1048576 + 114688);  // 65536 B
  float*    wvec = (float*)(ws + 1048576 + 180224);     // 1024 B
  float* outp = (float*)d_out;

  prep_kernel<<<1024, 256, 0, stream>>>(adj, W1, a1s, a1d, W2, a2s, a2d, Wo1, Wo2,
                                        cntp, W1F, W2F, Wo1F, Wo2F, wvec);
  fused_kernel<<<2048, 256, 0, stream>>>(obs, actn, cntp, W1F, W2F, b1, b2,
                                         Wo1F, bo1, g1, be1, Wo2F, bo2, g2, be2,
                                         Wo3, bo3, wvec, outp);
}